// Round 1
// baseline (2023.304 us; speedup 1.0000x reference)
//
#include <hip/hip_runtime.h>
#include <math.h>

// ---------------- problem constants ----------------
constexpr int NN = 8192;          // nodes
constexpr int EE = 65536;         // original edges
constexpr int ET = EE + NN;       // edges incl self loops = 73728
constexpr int GG = 64;            // graphs
constexpr int CC = 256;           // per-head channels
constexpr float SLOPE = 0.2f;

// ---------------- helpers ----------------
// order-preserving float<->unsigned encoding for atomicMax-based segment max.
// memset(0) < enc(-inf) so zero-init is a valid "-inf".
__device__ __forceinline__ unsigned enc_f(float f) {
  unsigned u = __float_as_uint(f);
  return (u & 0x80000000u) ? ~u : (u | 0x80000000u);
}
__device__ __forceinline__ float dec_f(unsigned e) {
  return (e & 0x80000000u) ? __uint_as_float(e & 0x7FFFFFFFu) : __uint_as_float(~e);
}

// ---------------- self-loop edge-attr mean ----------------
// deg[d] += 1 (once per edge), easum[d][k] += ea[e][k]
__global__ __launch_bounds__(256) void k_deg_easum(
    const int* __restrict__ ei, const float* __restrict__ ea,
    float* __restrict__ easum, float* __restrict__ deg) {
  int gid = blockIdx.x * 256 + threadIdx.x;      // EE*32 threads
  int e = gid >> 5, k = gid & 31;
  int d = ei[EE + e];
  atomicAdd(easum + (size_t)d * 32 + k, ea[(size_t)e * 32 + k]);
  if (k == 0) atomicAdd(deg + d, 1.0f);
}

// loop_ea = easum / max(deg,1)   (in place)
__global__ __launch_bounds__(256) void k_loop_ea(float* __restrict__ easum,
                                                 const float* __restrict__ deg) {
  int i = blockIdx.x * 256 + threadIdx.x;        // NN*32
  int n = i >> 5;
  easum[i] /= fmaxf(deg[n], 1.0f);
}

// ---------------- CSR build (edges sorted by dst) ----------------
__global__ __launch_bounds__(256) void k_counts(const int* __restrict__ ei,
                                                int* __restrict__ cnt) {
  int e = blockIdx.x * 256 + threadIdx.x;        // ET
  int d = (e < EE) ? ei[EE + e] : (e - EE);
  atomicAdd(cnt + d, 1);
}

// single-block exclusive scan over NN=8192 counts (1024 threads x 8)
__global__ __launch_bounds__(1024) void k_scan(const int* __restrict__ cnt,
                                               int* __restrict__ indptr,
                                               int* __restrict__ wpos) {
  __shared__ int sums[1024];
  int t = threadIdx.x;
  int local[8];
  int s = 0;
  #pragma unroll
  for (int i = 0; i < 8; ++i) { local[i] = s; s += cnt[t * 8 + i]; }
  sums[t] = s;
  __syncthreads();
  for (int off = 1; off < 1024; off <<= 1) {
    int v = (t >= off) ? sums[t - off] : 0;
    __syncthreads();
    sums[t] += v;
    __syncthreads();
  }
  int base = (t == 0) ? 0 : sums[t - 1];
  #pragma unroll
  for (int i = 0; i < 8; ++i) {
    int v = base + local[i];
    indptr[t * 8 + i] = v;
    wpos[t * 8 + i] = v;
  }
  if (t == 1023) indptr[NN] = sums[1023];
}

__global__ __launch_bounds__(256) void k_fill(const int* __restrict__ ei,
                                              int* __restrict__ wpos,
                                              int* __restrict__ ebyd,
                                              int* __restrict__ dstp) {
  int e = blockIdx.x * 256 + threadIdx.x;        // ET
  int d = (e < EE) ? ei[EE + e] : (e - EE);
  int idx = atomicAdd(wpos + d, 1);
  ebyd[idx] = e;
  dstp[idx] = d;
}

// ---------------- generic fp32 GEMM:  C[M,Nc] = A[M,K] @ B[Nc,K]^T + bias ----------------
// 64x64 tile, BK=16, 256 threads, 4x4 per thread. All dims used are multiples of {64,64,16}.
__global__ __launch_bounds__(256) void gemm_nt(
    const float* __restrict__ A, const float* __restrict__ Bm,
    const float* __restrict__ bias, float* __restrict__ Cm,
    int M, int Nc, int K, int act /*0 none,1 relu*/) {
  __shared__ float As[16][68];   // row stride 68: 16B-aligned rows, writes only 2-way conflicted
  __shared__ float Bs[16][68];
  const int tid = threadIdx.x;
  const int tx = tid & 15, ty = tid >> 4;
  const int m0 = blockIdx.y * 64, n0 = blockIdx.x * 64;
  float acc[4][4] = {};
  for (int k0 = 0; k0 < K; k0 += 16) {
    int r = tid >> 2;             // 0..63
    int c4 = (tid & 3) * 4;       // 0,4,8,12
    float4 va = *reinterpret_cast<const float4*>(A + (size_t)(m0 + r) * K + k0 + c4);
    float4 vb = *reinterpret_cast<const float4*>(Bm + (size_t)(n0 + r) * K + k0 + c4);
    As[c4 + 0][r] = va.x; As[c4 + 1][r] = va.y; As[c4 + 2][r] = va.z; As[c4 + 3][r] = va.w;
    Bs[c4 + 0][r] = vb.x; Bs[c4 + 1][r] = vb.y; Bs[c4 + 2][r] = vb.z; Bs[c4 + 3][r] = vb.w;
    __syncthreads();
    #pragma unroll
    for (int k = 0; k < 16; ++k) {
      float a[4], b[4];
      #pragma unroll
      for (int i = 0; i < 4; ++i) a[i] = As[k][ty * 4 + i];
      #pragma unroll
      for (int j = 0; j < 4; ++j) b[j] = Bs[k][tx * 4 + j];
      #pragma unroll
      for (int i = 0; i < 4; ++i)
        #pragma unroll
        for (int j = 0; j < 4; ++j) acc[i][j] = fmaf(a[i], b[j], acc[i][j]);
    }
    __syncthreads();
  }
  #pragma unroll
  for (int i = 0; i < 4; ++i) {
    int m = m0 + ty * 4 + i;
    #pragma unroll
    for (int j = 0; j < 4; ++j) {
      int n = n0 + tx * 4 + j;
      float v = acc[i][j] + (bias ? bias[n] : 0.0f);
      if (act == 1) v = fmaxf(v, 0.0f);
      Cm[(size_t)m * Nc + n] = v;
    }
  }
}

// ---------------- per-edge logit pass ----------------
// logit[p,h] = sum_c att[h*C+c] * leaky( xl[src,h*C+c] + xr[dst,h*C+c] + (ea . We_row) )
// Block = 32 edges (dst-sorted order), 8 lanes/edge. We staged in LDS in 128-channel chunks.
template <int H, int F>
__global__ __launch_bounds__(256) void k_edge_logits(
    const int* __restrict__ ebyd, const int* __restrict__ ei,
    const float* __restrict__ edge_attr, const float* __restrict__ loop_ea,
    const float* __restrict__ xl, const float* __restrict__ xr,
    const float* __restrict__ We, const float* __restrict__ att,
    float* __restrict__ L) {
  constexpr int JC = 128;
  __shared__ float ea_s[32][36];
  __shared__ float we_s[JC][36];
  __shared__ int ss[32], dd[32];
  const int tid = threadIdx.x;
  const int pbase = blockIdx.x * 32;
  const int es = tid >> 3;        // edge slot 0..31
  const int l8 = tid & 7;         // lane within slot

  if (tid < 32) {
    int e = ebyd[pbase + tid];
    int s, d;
    if (e < EE) { s = ei[e]; d = ei[EE + e]; }
    else { s = d = e - EE; }
    ss[tid] = s; dd[tid] = d;
  }
  {
    int k4 = l8 * 4;
    int e = ebyd[pbase + es];
    const float* srcp = (e < EE) ? (edge_attr + (size_t)e * 32 + k4)
                                 : (loop_ea + (size_t)(e - EE) * 32 + k4);
    float4 v = *reinterpret_cast<const float4*>(srcp);
    ea_s[es][k4 + 0] = v.x; ea_s[es][k4 + 1] = v.y;
    ea_s[es][k4 + 2] = v.z; ea_s[es][k4 + 3] = v.w;
  }

  float acc = 0.0f;
  for (int jc = 0; jc < F; jc += JC) {
    __syncthreads();              // protects we_s reuse (and initial ea_s/ss writes)
    {
      int base = tid * 16;        // 128*32 = 4096 floats / 256 threads
      #pragma unroll
      for (int u = 0; u < 4; ++u) {
        int idx = base + u * 4;
        int row = idx >> 5, col = idx & 31;
        float4 v = *reinterpret_cast<const float4*>(We + (size_t)(jc + row) * 32 + col);
        we_s[row][col + 0] = v.x; we_s[row][col + 1] = v.y;
        we_s[row][col + 2] = v.z; we_s[row][col + 3] = v.w;
      }
    }
    __syncthreads();
    const int s = ss[es], d = dd[es];
    const float* xlrow = xl + (size_t)s * F + jc;
    const float* xrrow = xr + (size_t)d * F + jc;
    #pragma unroll
    for (int q = 0; q < JC / 8; ++q) {
      int jj = l8 + q * 8;        // stride-1 across the 8 lanes -> conflict-free LDS
      float ee = 0.0f;
      #pragma unroll
      for (int k = 0; k < 32; ++k) ee = fmaf(ea_s[es][k], we_s[jj][k], ee);
      float m = xlrow[jj] + xrrow[jj] + ee;
      m = (m > 0.0f) ? m : (SLOPE * m);
      acc = fmaf(m, att[jc + jj], acc);
    }
    if ((jc & 255) == 128) {      // finished a head (2 chunks of 128)
      float r = acc;
      r += __shfl_xor(r, 1);
      r += __shfl_xor(r, 2);
      r += __shfl_xor(r, 4);
      if (l8 == 0) L[(size_t)(pbase + es) * H + (jc >> 8)] = r;
      acc = 0.0f;
    }
  }
}

// ---------------- segment softmax ----------------
template <int H>
__global__ __launch_bounds__(256) void k_segmax(const float* __restrict__ L,
                                                const int* __restrict__ dstp,
                                                unsigned* __restrict__ mx) {
  int i = blockIdx.x * 256 + threadIdx.x;        // ET*H
  int p = i / H, h = i - p * H;
  atomicMax(mx + (size_t)dstp[p] * H + h, enc_f(L[i]));
}

template <int H>
__global__ __launch_bounds__(256) void k_exp_den(float* __restrict__ L,
                                                 const int* __restrict__ dstp,
                                                 const unsigned* __restrict__ mx,
                                                 float* __restrict__ den) {
  int i = blockIdx.x * 256 + threadIdx.x;        // ET*H
  int p = i / H, h = i - p * H;
  int d = dstp[p];
  float ex = expf(L[i] - dec_f(mx[(size_t)d * H + h]));
  L[i] = ex;
  atomicAdd(den + (size_t)d * H + h, ex);
}

__global__ __launch_bounds__(256) void k_invden(float* __restrict__ den) {
  int i = blockIdx.x * 256 + threadIdx.x;
  den[i] = 1.0f / den[i];        // every node has a self loop -> den > 0
}

// ---------------- alpha-weighted aggregation (CSR, atomic-free) ----------------
template <int H, int F, bool RELU>
__global__ __launch_bounds__(256) void k_aggregate(
    const int* __restrict__ indptr, const int* __restrict__ ebyd,
    const int* __restrict__ ei, const float* __restrict__ L,
    const float* __restrict__ invden, const float* __restrict__ xl,
    const float* __restrict__ bias, float* __restrict__ out) {
  constexpr int CPE = F / 256;
  const int n = blockIdx.x;
  const int tid = threadIdx.x;
  const int j0 = tid * CPE;
  const int h = j0 >> 8;         // CC=256 channels per head
  const float invd = invden[(size_t)n * H + h];
  float acc[CPE] = {};
  const int p0 = indptr[n], p1 = indptr[n + 1];
  for (int p = p0; p < p1; ++p) {
    int e = ebyd[p];
    int s = (e < EE) ? ei[e] : (e - EE);
    float a = L[(size_t)p * H + h] * invd;
    const float* row = xl + (size_t)s * F + j0;
    #pragma unroll
    for (int q = 0; q < CPE; q += 4) {
      float4 v = *reinterpret_cast<const float4*>(row + q);
      acc[q + 0] = fmaf(a, v.x, acc[q + 0]);
      acc[q + 1] = fmaf(a, v.y, acc[q + 1]);
      acc[q + 2] = fmaf(a, v.z, acc[q + 2]);
      acc[q + 3] = fmaf(a, v.w, acc[q + 3]);
    }
  }
  #pragma unroll
  for (int q = 0; q < CPE; ++q) {
    float v = acc[q] + bias[j0 + q];
    if (RELU) v = fmaxf(v, 0.0f);
    out[(size_t)n * F + j0 + q] = v;
  }
}

// ---------------- pooling + MLP head ----------------
__global__ __launch_bounds__(256) void k_pool(const float* __restrict__ h2,
                                              const int* __restrict__ batch,
                                              float* __restrict__ pooled) {
  int i = blockIdx.x * 256 + threadIdx.x;        // NN*1024
  int n = i >> 10, j = i & 1023;
  atomicAdd(pooled + (size_t)batch[n] * 1024 + j, h2[i]);
}

__global__ __launch_bounds__(256) void k_pcnt(const int* __restrict__ batch,
                                              int* __restrict__ pcnt) {
  int n = blockIdx.x * 256 + threadIdx.x;
  atomicAdd(pcnt + batch[n], 1);
}

__global__ __launch_bounds__(256) void k_pooldiv(float* __restrict__ pooled,
                                                 const int* __restrict__ pcnt) {
  int i = blockIdx.x * 256 + threadIdx.x;        // GG*1024
  int g = i >> 10;
  pooled[i] = pooled[i] / fmaxf((float)pcnt[g], 1.0f);
}

__global__ __launch_bounds__(64) void k_head(const float* __restrict__ m2,
                                             const float* __restrict__ W3,
                                             const float* __restrict__ b3,
                                             float* __restrict__ out) {
  int g = threadIdx.x;           // 64 graphs
  float a = 0.0f;
  for (int k = 0; k < 256; ++k) a = fmaf(m2[(size_t)g * 256 + k], W3[k], a);
  a += b3[0];
  out[g] = 1.0f / (1.0f + expf(-a));
}

// ---------------- launch ----------------
extern "C" void kernel_launch(void* const* d_in, const int* in_sizes, int n_in,
                              void* d_out, int out_size, void* d_ws, size_t ws_size,
                              hipStream_t stream) {
  const float* x    = (const float*)d_in[0];
  const int*   ei   = (const int*)d_in[1];     // [2,EE] (JAX x64 disabled -> int32)
  const float* ea   = (const float*)d_in[2];
  const int*   batch= (const int*)d_in[3];
  const float* Wl1  = (const float*)d_in[4];
  const float* bl1  = (const float*)d_in[5];
  const float* Wr1  = (const float*)d_in[6];
  const float* br1  = (const float*)d_in[7];
  const float* We1  = (const float*)d_in[8];
  const float* att1 = (const float*)d_in[9];
  const float* bias1= (const float*)d_in[10];
  const float* Wl2  = (const float*)d_in[11];
  const float* bl2  = (const float*)d_in[12];
  const float* Wr2  = (const float*)d_in[13];
  const float* br2  = (const float*)d_in[14];
  const float* We2  = (const float*)d_in[15];
  const float* att2 = (const float*)d_in[16];
  const float* bias2= (const float*)d_in[17];
  const float* W1   = (const float*)d_in[18];
  const float* b1   = (const float*)d_in[19];
  const float* W2   = (const float*)d_in[20];
  const float* b2   = (const float*)d_in[21];
  const float* W3   = (const float*)d_in[22];
  const float* b3   = (const float*)d_in[23];
  float* out = (float*)d_out;

  char* w = (char*)d_ws;
  size_t off = 0;
  auto take = [&](size_t b) { size_t r = off; off = (off + b + 255) & ~(size_t)255; return r; };

  size_t xl_off  = take((size_t)NN * 2048 * 4);
  size_t xr_off  = take((size_t)NN * 2048 * 4);
  size_t h_off   = take((size_t)NN * 2048 * 4);
  size_t L_off   = take((size_t)ET * 8 * 4);
  size_t z1      = off;                       // ---- zero zone 1 start ----
  size_t ea_off  = take((size_t)NN * 32 * 4);
  size_t deg_off = take((size_t)NN * 4);
  size_t cnt_off = take((size_t)NN * 4);
  size_t pool_off= take((size_t)GG * 1024 * 4);
  size_t pcnt_off= take((size_t)GG * 4);
  size_t z2      = off;                       // ---- zero zone 2 (re-zeroed for layer 2) ----
  size_t den_off = take((size_t)NN * 8 * 4);
  size_t max_off = take((size_t)NN * 8 * 4);
  size_t z2e     = off;
  size_t ip_off  = take((size_t)(NN + 1) * 4);
  size_t wp_off  = take((size_t)NN * 4);
  size_t eb_off  = take((size_t)ET * 4);
  size_t dp_off  = take((size_t)ET * 4);
  size_t m1_off  = take((size_t)GG * 512 * 4);
  size_t m2_off  = take((size_t)GG * 256 * 4);
  (void)ws_size; (void)n_in; (void)in_sizes; (void)out_size;

  float*    xlb   = (float*)(w + xl_off);
  float*    xrb   = (float*)(w + xr_off);
  float*    hb    = (float*)(w + h_off);
  float*    Lb    = (float*)(w + L_off);
  float*    eab   = (float*)(w + ea_off);
  float*    degb  = (float*)(w + deg_off);
  int*      cntb  = (int*)(w + cnt_off);
  float*    poolb = (float*)(w + pool_off);
  int*      pcntb = (int*)(w + pcnt_off);
  float*    denb  = (float*)(w + den_off);
  unsigned* maxb  = (unsigned*)(w + max_off);
  int*      ipb   = (int*)(w + ip_off);
  int*      wpb   = (int*)(w + wp_off);
  int*      ebb   = (int*)(w + eb_off);
  int*      dpb   = (int*)(w + dp_off);
  float*    m1b   = (float*)(w + m1_off);
  float*    m2b   = (float*)(w + m2_off);

  hipMemsetAsync(w + z1, 0, z2e - z1, stream);

  // self-loop edge attrs + CSR
  k_deg_easum<<<EE * 32 / 256, 256, 0, stream>>>(ei, ea, eab, degb);
  k_loop_ea<<<NN * 32 / 256, 256, 0, stream>>>(eab, degb);
  k_counts<<<ET / 256, 256, 0, stream>>>(ei, cntb);
  k_scan<<<1, 1024, 0, stream>>>(cntb, ipb, wpb);
  k_fill<<<ET / 256, 256, 0, stream>>>(ei, wpb, ebb, dpb);

  // ---- layer 1 (H=8, F=2048) ----
  gemm_nt<<<dim3(2048 / 64, NN / 64), 256, 0, stream>>>(x, Wl1, bl1, xlb, NN, 2048, 64, 0);
  gemm_nt<<<dim3(2048 / 64, NN / 64), 256, 0, stream>>>(x, Wr1, br1, xrb, NN, 2048, 64, 0);
  k_edge_logits<8, 2048><<<ET / 32, 256, 0, stream>>>(ebb, ei, ea, eab, xlb, xrb, We1, att1, Lb);
  k_segmax<8><<<ET * 8 / 256, 256, 0, stream>>>(Lb, dpb, maxb);
  k_exp_den<8><<<ET * 8 / 256, 256, 0, stream>>>(Lb, dpb, maxb, denb);
  k_invden<<<NN * 8 / 256, 256, 0, stream>>>(denb);
  k_aggregate<8, 2048, true><<<NN, 256, 0, stream>>>(ipb, ebb, ei, Lb, denb, xlb, bias1, hb);

  // ---- layer 2 (H=4, F=1024) ----
  gemm_nt<<<dim3(1024 / 64, NN / 64), 256, 0, stream>>>(hb, Wl2, bl2, xlb, NN, 1024, 2048, 0);
  gemm_nt<<<dim3(1024 / 64, NN / 64), 256, 0, stream>>>(hb, Wr2, br2, xrb, NN, 1024, 2048, 0);
  hipMemsetAsync(w + z2, 0, z2e - z2, stream);   // re-zero den/max
  k_edge_logits<4, 1024><<<ET / 32, 256, 0, stream>>>(ebb, ei, ea, eab, xlb, xrb, We2, att2, Lb);
  k_segmax<4><<<ET * 4 / 256, 256, 0, stream>>>(Lb, dpb, maxb);
  k_exp_den<4><<<ET * 4 / 256, 256, 0, stream>>>(Lb, dpb, maxb, denb);
  k_invden<<<NN * 4 / 256, 256, 0, stream>>>(denb);
  k_aggregate<4, 1024, false><<<NN, 256, 0, stream>>>(ipb, ebb, ei, Lb, denb, xlb, bias2, hb);

  // ---- pool + MLP ----
  k_pool<<<NN * 1024 / 256, 256, 0, stream>>>(hb, batch, poolb);
  k_pcnt<<<NN / 256, 256, 0, stream>>>(batch, pcntb);
  k_pooldiv<<<GG * 1024 / 256, 256, 0, stream>>>(poolb, pcntb);
  gemm_nt<<<dim3(512 / 64, 1), 256, 0, stream>>>(poolb, W1, b1, m1b, GG, 512, 1024, 1);
  gemm_nt<<<dim3(256 / 64, 1), 256, 0, stream>>>(m1b, W2, b2, m2b, GG, 256, 512, 1);
  k_head<<<1, 64, 0, stream>>>(m2b, W3, b3, out);
}

// Round 2
// 1328.259 us; speedup vs baseline: 1.5233x; 1.5233x over previous
//
#include <hip/hip_runtime.h>
#include <math.h>

// ---------------- problem constants ----------------
constexpr int NN = 8192;          // nodes
constexpr int EE = 65536;         // original edges
constexpr int ET = EE + NN;       // edges incl self loops = 73728
constexpr int GG = 64;            // graphs
constexpr float SLOPE = 0.2f;

using bf16 = __bf16;
using bf16x8 = __bf16 __attribute__((ext_vector_type(8)));
using bf16x4 = __bf16 __attribute__((ext_vector_type(4)));
using f32x4v = float __attribute__((ext_vector_type(4)));

// ---------------- helpers ----------------
__device__ __forceinline__ unsigned enc_f(float f) {
  unsigned u = __float_as_uint(f);
  return (u & 0x80000000u) ? ~u : (u | 0x80000000u);
}
__device__ __forceinline__ float dec_f(unsigned e) {
  return (e & 0x80000000u) ? __uint_as_float(e & 0x7FFFFFFFu) : __uint_as_float(~e);
}

// async global->LDS, 16B per lane. LDS dest must be WAVE-UNIFORM base (+lane*16 by HW).
__device__ __forceinline__ void gl2lds16(const void* g, void* l) {
  __builtin_amdgcn_global_load_lds(
      (const __attribute__((address_space(1))) void*)g,
      (__attribute__((address_space(3))) void*)l, 16, 0, 0);
}

// ---------------- CSR build (edges sorted by dst) ----------------
__global__ __launch_bounds__(256) void k_counts(const int* __restrict__ ei,
                                                int* __restrict__ cnt) {
  int e = blockIdx.x * 256 + threadIdx.x;        // ET
  int d = (e < EE) ? ei[EE + e] : (e - EE);
  atomicAdd(cnt + d, 1);
}

__global__ __launch_bounds__(1024) void k_scan(const int* __restrict__ cnt,
                                               int* __restrict__ indptr,
                                               int* __restrict__ wpos) {
  __shared__ int sums[1024];
  int t = threadIdx.x;
  int local[8];
  int s = 0;
  #pragma unroll
  for (int i = 0; i < 8; ++i) { local[i] = s; s += cnt[t * 8 + i]; }
  sums[t] = s;
  __syncthreads();
  for (int off = 1; off < 1024; off <<= 1) {
    int v = (t >= off) ? sums[t - off] : 0;
    __syncthreads();
    sums[t] += v;
    __syncthreads();
  }
  int base = (t == 0) ? 0 : sums[t - 1];
  #pragma unroll
  for (int i = 0; i < 8; ++i) {
    int v = base + local[i];
    indptr[t * 8 + i] = v;
    wpos[t * 8 + i] = v;
  }
  if (t == 1023) indptr[NN] = sums[1023];
}

__global__ __launch_bounds__(256) void k_fill(const int* __restrict__ ei,
                                              int* __restrict__ wpos,
                                              int* __restrict__ ebyd,
                                              int* __restrict__ dstp) {
  int e = blockIdx.x * 256 + threadIdx.x;        // ET
  int d = (e < EE) ? ei[EE + e] : (e - EE);
  int idx = atomicAdd(wpos + d, 1);
  ebyd[idx] = e;
  dstp[idx] = d;
}

// self-loop edge attr = mean of incoming original edge attrs (atomic-free, via CSR)
__global__ __launch_bounds__(256) void k_loopea(const int* __restrict__ ip,
                                                const int* __restrict__ ebyd,
                                                const float* __restrict__ ea,
                                                float* __restrict__ easum) {
  int node = blockIdx.x * 8 + (threadIdx.x >> 5);
  int k = threadIdx.x & 31;
  float acc = 0.0f, deg = 0.0f;
  int p0 = ip[node], p1 = ip[node + 1];
  for (int p = p0; p < p1; ++p) {
    int e = ebyd[p];
    if (e < EE) { acc += ea[(size_t)e * 32 + k]; deg += 1.0f; }
  }
  easum[(size_t)node * 32 + k] = acc / fmaxf(deg, 1.0f);
}

// ---------------- fp32 -> split bf16 [hi | lo], row-major [M][2K] ----------------
__global__ __launch_bounds__(256) void k_split(const float* __restrict__ in,
                                               bf16* __restrict__ out,
                                               int K, int total4) {
  int i = blockIdx.x * 256 + threadIdx.x;
  if (i >= total4) return;
  int K4 = K >> 2;
  int m = i / K4, k4 = (i - m * K4) << 2;
  float4 v = *reinterpret_cast<const float4*>(in + (size_t)m * K + k4);
  float vv[4] = {v.x, v.y, v.z, v.w};
  bf16x4 hi, lo;
  #pragma unroll
  for (int u = 0; u < 4; ++u) {
    bf16 h = (bf16)vv[u];
    hi[u] = h;
    lo[u] = (bf16)(vv[u] - (float)h);
  }
  *reinterpret_cast<bf16x4*>(out + (size_t)m * 2 * K + k4) = hi;
  *reinterpret_cast<bf16x4*>(out + (size_t)m * 2 * K + K + k4) = lo;
}

// ---------------- split-bf16 MFMA GEMM ----------------
// Computes C[M][Nc] = A[M][K]B[Nc][K]^T + bias in ~fp32 precision via
// logical K' = 3*Ko walk over physical [hi|lo] storage (row stride 2*Ko):
//   k0 in [0,Ko): A_hi*B_hi;  [Ko,2Ko): A_hi*B_lo;  [2Ko,3Ko): A_lo*B_hi.
// m97 structure: 128x128 tile, BK=32, 4 waves (2x2), 4x4 frags of 16x16x32 bf16,
// global_load_lds width 16, linear LDS, 2 barriers per K-step.
__global__ __launch_bounds__(256) void gemm_mfma(
    const bf16* __restrict__ A, const bf16* __restrict__ B,
    const float* __restrict__ bias, float* __restrict__ C,
    int M, int Nc, int Ko) {
  __shared__ __attribute__((aligned(16))) bf16 As[128][32];
  __shared__ __attribute__((aligned(16))) bf16 Bs[128][32];
  const int tid = threadIdx.x;
  const int wave = tid >> 6, lane = tid & 63;
  const int wr = wave >> 1, wc = wave & 1;
  const int l16 = lane & 15, lk = lane >> 4;
  const int m0 = blockIdx.y * 128, n0 = blockIdx.x * 128;
  const int ld = 2 * Ko;
  // staging chunk for this thread: c = i*256 + tid, row=c>>2, col8=(c&3)*8
  const int r0 = tid >> 2, c8 = (tid & 3) * 8;

  f32x4v acc[4][4] = {};
  for (int k0 = 0; k0 < 3 * Ko; k0 += 32) {
    int ka = (k0 < Ko) ? k0 : k0 - Ko;          // A: hi, hi, lo
    int kb = (k0 < 2 * Ko) ? k0 : k0 - 2 * Ko;  // B: hi, lo, hi
    #pragma unroll
    for (int i = 0; i < 2; ++i) {
      int row = i * 64 + r0;
      bf16* abase = &As[0][0] + ((size_t)(i * 256 + wave * 64)) * 8;
      bf16* bbase = &Bs[0][0] + ((size_t)(i * 256 + wave * 64)) * 8;
      gl2lds16(A + (size_t)(m0 + row) * ld + ka + c8, abase);
      gl2lds16(B + (size_t)(n0 + row) * ld + kb + c8, bbase);
    }
    __syncthreads();
    bf16x8 af[4], bfr[4];
    #pragma unroll
    for (int mi = 0; mi < 4; ++mi)
      af[mi] = *reinterpret_cast<const bf16x8*>(&As[wr * 64 + mi * 16 + l16][lk * 8]);
    #pragma unroll
    for (int ni = 0; ni < 4; ++ni)
      bfr[ni] = *reinterpret_cast<const bf16x8*>(&Bs[wc * 64 + ni * 16 + l16][lk * 8]);
    #pragma unroll
    for (int mi = 0; mi < 4; ++mi)
      #pragma unroll
      for (int ni = 0; ni < 4; ++ni)
        acc[mi][ni] = __builtin_amdgcn_mfma_f32_16x16x32_bf16(af[mi], bfr[ni],
                                                              acc[mi][ni], 0, 0, 0);
    __syncthreads();
  }
  // C/D layout (m89-verified): col = lane&15, row = (lane>>4)*4 + reg
  #pragma unroll
  for (int mi = 0; mi < 4; ++mi) {
    #pragma unroll
    for (int ni = 0; ni < 4; ++ni) {
      int col = n0 + wc * 64 + ni * 16 + l16;
      float bv = bias ? bias[col] : 0.0f;
      #pragma unroll
      for (int j = 0; j < 4; ++j) {
        int row = m0 + wr * 64 + mi * 16 + lk * 4 + j;
        C[(size_t)row * Nc + col] = acc[mi][ni][j] + bv;
      }
    }
  }
}

// ---------------- fp32 GEMM (kept for tiny MLP head) ----------------
__global__ __launch_bounds__(256) void gemm_nt(
    const float* __restrict__ A, const float* __restrict__ Bm,
    const float* __restrict__ bias, float* __restrict__ Cm,
    int M, int Nc, int K, int act) {
  __shared__ float As[16][68];
  __shared__ float Bs[16][68];
  const int tid = threadIdx.x;
  const int tx = tid & 15, ty = tid >> 4;
  const int m0 = blockIdx.y * 64, n0 = blockIdx.x * 64;
  float acc[4][4] = {};
  for (int k0 = 0; k0 < K; k0 += 16) {
    int r = tid >> 2;
    int c4 = (tid & 3) * 4;
    float4 va = *reinterpret_cast<const float4*>(A + (size_t)(m0 + r) * K + k0 + c4);
    float4 vb = *reinterpret_cast<const float4*>(Bm + (size_t)(n0 + r) * K + k0 + c4);
    As[c4 + 0][r] = va.x; As[c4 + 1][r] = va.y; As[c4 + 2][r] = va.z; As[c4 + 3][r] = va.w;
    Bs[c4 + 0][r] = vb.x; Bs[c4 + 1][r] = vb.y; Bs[c4 + 2][r] = vb.z; Bs[c4 + 3][r] = vb.w;
    __syncthreads();
    #pragma unroll
    for (int k = 0; k < 16; ++k) {
      float a[4], b[4];
      #pragma unroll
      for (int i = 0; i < 4; ++i) a[i] = As[k][ty * 4 + i];
      #pragma unroll
      for (int j = 0; j < 4; ++j) b[j] = Bs[k][tx * 4 + j];
      #pragma unroll
      for (int i = 0; i < 4; ++i)
        #pragma unroll
        for (int j = 0; j < 4; ++j) acc[i][j] = fmaf(a[i], b[j], acc[i][j]);
    }
    __syncthreads();
  }
  #pragma unroll
  for (int i = 0; i < 4; ++i) {
    int m = m0 + ty * 4 + i;
    #pragma unroll
    for (int j = 0; j < 4; ++j) {
      int n = n0 + tx * 4 + j;
      float v = acc[i][j] + (bias ? bias[n] : 0.0f);
      if (act == 1) v = fmaxf(v, 0.0f);
      Cm[(size_t)m * Nc + n] = v;
    }
  }
}

// ---------------- per-edge logit pass ----------------
template <int H, int F>
__global__ __launch_bounds__(256) void k_edge_logits(
    const int* __restrict__ ebyd, const int* __restrict__ ei,
    const float* __restrict__ edge_attr, const float* __restrict__ loop_ea,
    const float* __restrict__ xl, const float* __restrict__ xr,
    const float* __restrict__ We, const float* __restrict__ att,
    float* __restrict__ L) {
  constexpr int JC = 128;
  __shared__ float ea_s[32][36];
  __shared__ float we_s[JC][36];
  __shared__ int ss[32], dd[32];
  const int tid = threadIdx.x;
  const int pbase = blockIdx.x * 32;
  const int es = tid >> 3;
  const int l8 = tid & 7;

  if (tid < 32) {
    int e = ebyd[pbase + tid];
    int s, d;
    if (e < EE) { s = ei[e]; d = ei[EE + e]; }
    else { s = d = e - EE; }
    ss[tid] = s; dd[tid] = d;
  }
  {
    int k4 = l8 * 4;
    int e = ebyd[pbase + es];
    const float* srcp = (e < EE) ? (edge_attr + (size_t)e * 32 + k4)
                                 : (loop_ea + (size_t)(e - EE) * 32 + k4);
    float4 v = *reinterpret_cast<const float4*>(srcp);
    ea_s[es][k4 + 0] = v.x; ea_s[es][k4 + 1] = v.y;
    ea_s[es][k4 + 2] = v.z; ea_s[es][k4 + 3] = v.w;
  }

  float acc = 0.0f;
  for (int jc = 0; jc < F; jc += JC) {
    __syncthreads();
    {
      int base = tid * 16;
      #pragma unroll
      for (int u = 0; u < 4; ++u) {
        int idx = base + u * 4;
        int row = idx >> 5, col = idx & 31;
        float4 v = *reinterpret_cast<const float4*>(We + (size_t)(jc + row) * 32 + col);
        we_s[row][col + 0] = v.x; we_s[row][col + 1] = v.y;
        we_s[row][col + 2] = v.z; we_s[row][col + 3] = v.w;
      }
    }
    __syncthreads();
    const int s = ss[es], d = dd[es];
    const float* xlrow = xl + (size_t)s * F + jc;
    const float* xrrow = xr + (size_t)d * F + jc;
    #pragma unroll
    for (int q = 0; q < JC / 8; ++q) {
      int jj = l8 + q * 8;
      float ee = 0.0f;
      #pragma unroll
      for (int k = 0; k < 32; ++k) ee = fmaf(ea_s[es][k], we_s[jj][k], ee);
      float m = xlrow[jj] + xrrow[jj] + ee;
      m = (m > 0.0f) ? m : (SLOPE * m);
      acc = fmaf(m, att[jc + jj], acc);
    }
    if ((jc & 255) == 128) {
      float r = acc;
      r += __shfl_xor(r, 1);
      r += __shfl_xor(r, 2);
      r += __shfl_xor(r, 4);
      if (l8 == 0) L[(size_t)(pbase + es) * H + (jc >> 8)] = r;
      acc = 0.0f;
    }
  }
}

// ---------------- segment softmax ----------------
template <int H>
__global__ __launch_bounds__(256) void k_segmax(const float* __restrict__ L,
                                                const int* __restrict__ dstp,
                                                unsigned* __restrict__ mx) {
  int i = blockIdx.x * 256 + threadIdx.x;
  int p = i / H, h = i - p * H;
  atomicMax(mx + (size_t)dstp[p] * H + h, enc_f(L[i]));
}

template <int H>
__global__ __launch_bounds__(256) void k_exp_den(float* __restrict__ L,
                                                 const int* __restrict__ dstp,
                                                 const unsigned* __restrict__ mx,
                                                 float* __restrict__ den) {
  int i = blockIdx.x * 256 + threadIdx.x;
  int p = i / H, h = i - p * H;
  int d = dstp[p];
  float ex = expf(L[i] - dec_f(mx[(size_t)d * H + h]));
  L[i] = ex;
  atomicAdd(den + (size_t)d * H + h, ex);
}

__global__ __launch_bounds__(256) void k_invden(float* __restrict__ den) {
  int i = blockIdx.x * 256 + threadIdx.x;
  den[i] = 1.0f / den[i];
}

// ---------------- alpha-weighted aggregation (CSR, atomic-free) ----------------
// SPLIT=true: apply relu and emit split-bf16 [hi|lo] rows (stride 2F) for next GEMM.
template <int H, int F, bool SPLIT>
__global__ __launch_bounds__(256) void k_aggregate(
    const int* __restrict__ indptr, const int* __restrict__ ebyd,
    const int* __restrict__ ei, const float* __restrict__ L,
    const float* __restrict__ invden, const float* __restrict__ xl,
    const float* __restrict__ bias, float* __restrict__ out,
    bf16* __restrict__ outs) {
  constexpr int CPE = F / 256;
  const int n = blockIdx.x;
  const int tid = threadIdx.x;
  const int j0 = tid * CPE;
  const int h = j0 >> 8;
  const float invd = invden[(size_t)n * H + h];
  float acc[CPE] = {};
  const int p0 = indptr[n], p1 = indptr[n + 1];
  for (int p = p0; p < p1; ++p) {
    int e = ebyd[p];
    int s = (e < EE) ? ei[e] : (e - EE);
    float a = L[(size_t)p * H + h] * invd;
    const float* row = xl + (size_t)s * F + j0;
    #pragma unroll
    for (int q = 0; q < CPE; q += 4) {
      float4 v = *reinterpret_cast<const float4*>(row + q);
      acc[q + 0] = fmaf(a, v.x, acc[q + 0]);
      acc[q + 1] = fmaf(a, v.y, acc[q + 1]);
      acc[q + 2] = fmaf(a, v.z, acc[q + 2]);
      acc[q + 3] = fmaf(a, v.w, acc[q + 3]);
    }
  }
  #pragma unroll
  for (int q = 0; q < CPE; ++q) {
    float v = acc[q] + bias[j0 + q];
    if (SPLIT) {
      v = fmaxf(v, 0.0f);
      bf16 hi = (bf16)v;
      outs[(size_t)n * (2 * F) + j0 + q] = hi;
      outs[(size_t)n * (2 * F) + F + j0 + q] = (bf16)(v - (float)hi);
    } else {
      out[(size_t)n * F + j0 + q] = v;
    }
  }
}

// ---------------- pooling (batch is sorted -> segmented mean) ----------------
__global__ __launch_bounds__(64) void k_gstart(const int* __restrict__ batch,
                                               int* __restrict__ gstart) {
  int g = threadIdx.x;            // 64 graphs
  int lo = 0, hi = NN;
  while (lo < hi) { int mid = (lo + hi) >> 1; if (batch[mid] < g) lo = mid + 1; else hi = mid; }
  gstart[g] = lo;
  if (g == 63) gstart[64] = NN;
}

__global__ __launch_bounds__(256) void k_pool2(const float* __restrict__ h2,
                                               const int* __restrict__ gstart,
                                               float* __restrict__ pooled) {
  int g = blockIdx.y;
  int j = blockIdx.x * 256 + threadIdx.x;   // 0..1023
  int s = gstart[g], e2 = gstart[g + 1];
  float acc = 0.0f;
  for (int n = s; n < e2; ++n) acc += h2[(size_t)n * 1024 + j];
  pooled[(size_t)g * 1024 + j] = acc / fmaxf((float)(e2 - s), 1.0f);
}

__global__ __launch_bounds__(64) void k_head(const float* __restrict__ m2,
                                             const float* __restrict__ W3,
                                             const float* __restrict__ b3,
                                             float* __restrict__ out) {
  int g = threadIdx.x;
  float a = 0.0f;
  for (int k = 0; k < 256; ++k) a = fmaf(m2[(size_t)g * 256 + k], W3[k], a);
  a += b3[0];
  out[g] = 1.0f / (1.0f + expf(-a));
}

// ---------------- launch ----------------
extern "C" void kernel_launch(void* const* d_in, const int* in_sizes, int n_in,
                              void* d_out, int out_size, void* d_ws, size_t ws_size,
                              hipStream_t stream) {
  const float* x    = (const float*)d_in[0];
  const int*   ei   = (const int*)d_in[1];
  const float* ea   = (const float*)d_in[2];
  const int*   batch= (const int*)d_in[3];
  const float* Wl1  = (const float*)d_in[4];
  const float* bl1  = (const float*)d_in[5];
  const float* Wr1  = (const float*)d_in[6];
  const float* br1  = (const float*)d_in[7];
  const float* We1  = (const float*)d_in[8];
  const float* att1 = (const float*)d_in[9];
  const float* bias1= (const float*)d_in[10];
  const float* Wl2  = (const float*)d_in[11];
  const float* bl2  = (const float*)d_in[12];
  const float* Wr2  = (const float*)d_in[13];
  const float* br2  = (const float*)d_in[14];
  const float* We2  = (const float*)d_in[15];
  const float* att2 = (const float*)d_in[16];
  const float* bias2= (const float*)d_in[17];
  const float* W1   = (const float*)d_in[18];
  const float* b1   = (const float*)d_in[19];
  const float* W2   = (const float*)d_in[20];
  const float* b2   = (const float*)d_in[21];
  const float* W3   = (const float*)d_in[22];
  const float* b3   = (const float*)d_in[23];
  float* out = (float*)d_out;

  char* w = (char*)d_ws;
  size_t off = 0;
  auto take = [&](size_t b) { size_t r = off; off = (off + b + 255) & ~(size_t)255; return r; };

  size_t xl_off  = take((size_t)NN * 2048 * 4);   // layer1 xl; layer2 xl in [0,32MB), h2 in [32,64MB)
  size_t xr_off  = take((size_t)NN * 2048 * 4);
  size_t hs_off  = take((size_t)NN * 4096 * 2);   // split bf16 of relu(h1): [hi|lo], stride 4096
  size_t xs_off  = take((size_t)NN * 128 * 2);    // split bf16 of x, stride 128
  size_t wl1s_off= take((size_t)2048 * 128 * 2);
  size_t wr1s_off= take((size_t)2048 * 128 * 2);
  size_t wl2s_off= take((size_t)1024 * 4096 * 2);
  size_t wr2s_off= take((size_t)1024 * 4096 * 2);
  size_t L_off   = take((size_t)ET * 8 * 4);
  size_t z1      = off;                           // ---- zero zone: cnt | den | max ----
  size_t cnt_off = take((size_t)NN * 4);
  size_t z2      = off;                           // ---- re-zeroed before layer 2 ----
  size_t den_off = take((size_t)NN * 8 * 4);
  size_t max_off = take((size_t)NN * 8 * 4);
  size_t z2e     = off;
  size_t ea_off  = take((size_t)NN * 32 * 4);
  size_t ip_off  = take((size_t)(NN + 1) * 4);
  size_t wp_off  = take((size_t)NN * 4);
  size_t eb_off  = take((size_t)ET * 4);
  size_t dp_off  = take((size_t)ET * 4);
  size_t gs_off  = take((size_t)65 * 4);
  size_t pool_off= take((size_t)GG * 1024 * 4);
  size_t m1_off  = take((size_t)GG * 512 * 4);
  size_t m2_off  = take((size_t)GG * 256 * 4);
  (void)ws_size; (void)n_in; (void)in_sizes; (void)out_size;

  float*    xlb   = (float*)(w + xl_off);
  float*    xrb   = (float*)(w + xr_off);
  float*    h2b   = (float*)(w + xl_off) + (size_t)NN * 1024;   // upper half of xl buffer
  bf16*     hsb   = (bf16*)(w + hs_off);
  bf16*     xsb   = (bf16*)(w + xs_off);
  bf16*     wl1s  = (bf16*)(w + wl1s_off);
  bf16*     wr1s  = (bf16*)(w + wr1s_off);
  bf16*     wl2s  = (bf16*)(w + wl2s_off);
  bf16*     wr2s  = (bf16*)(w + wr2s_off);
  float*    Lb    = (float*)(w + L_off);
  int*      cntb  = (int*)(w + cnt_off);
  float*    denb  = (float*)(w + den_off);
  unsigned* maxb  = (unsigned*)(w + max_off);
  float*    eab   = (float*)(w + ea_off);
  int*      ipb   = (int*)(w + ip_off);
  int*      wpb   = (int*)(w + wp_off);
  int*      ebb   = (int*)(w + eb_off);
  int*      dpb   = (int*)(w + dp_off);
  int*      gsb   = (int*)(w + gs_off);
  float*    poolb = (float*)(w + pool_off);
  float*    m1b   = (float*)(w + m1_off);
  float*    m2b   = (float*)(w + m2_off);

  hipMemsetAsync(w + z1, 0, z2e - z1, stream);

  // CSR + self-loop edge attrs
  k_counts<<<ET / 256, 256, 0, stream>>>(ei, cntb);
  k_scan<<<1, 1024, 0, stream>>>(cntb, ipb, wpb);
  k_fill<<<ET / 256, 256, 0, stream>>>(ei, wpb, ebb, dpb);
  k_loopea<<<NN / 8, 256, 0, stream>>>(ipb, ebb, ea, eab);

  // split conversions
  k_split<<<(NN * 64 / 4 + 255) / 256, 256, 0, stream>>>(x, xsb, 64, NN * 64 / 4);
  k_split<<<(2048 * 64 / 4 + 255) / 256, 256, 0, stream>>>(Wl1, wl1s, 64, 2048 * 64 / 4);
  k_split<<<(2048 * 64 / 4 + 255) / 256, 256, 0, stream>>>(Wr1, wr1s, 64, 2048 * 64 / 4);
  k_split<<<(1024 * 2048 / 4 + 255) / 256, 256, 0, stream>>>(Wl2, wl2s, 2048, 1024 * 2048 / 4);
  k_split<<<(1024 * 2048 / 4 + 255) / 256, 256, 0, stream>>>(Wr2, wr2s, 2048, 1024 * 2048 / 4);

  // ---- layer 1 (H=8, F=2048), K'=3*64 ----
  gemm_mfma<<<dim3(2048 / 128, NN / 128), 256, 0, stream>>>(xsb, wl1s, bl1, xlb, NN, 2048, 64);
  gemm_mfma<<<dim3(2048 / 128, NN / 128), 256, 0, stream>>>(xsb, wr1s, br1, xrb, NN, 2048, 64);
  k_edge_logits<8, 2048><<<ET / 32, 256, 0, stream>>>(ebb, ei, ea, eab, xlb, xrb, We1, att1, Lb);
  k_segmax<8><<<ET * 8 / 256, 256, 0, stream>>>(Lb, dpb, maxb);
  k_exp_den<8><<<ET * 8 / 256, 256, 0, stream>>>(Lb, dpb, maxb, denb);
  k_invden<<<NN * 8 / 256, 256, 0, stream>>>(denb);
  k_aggregate<8, 2048, true><<<NN, 256, 0, stream>>>(ipb, ebb, ei, Lb, denb, xlb, bias1,
                                                     nullptr, hsb);

  // ---- layer 2 (H=4, F=1024), K'=3*2048 ----
  gemm_mfma<<<dim3(1024 / 128, NN / 128), 256, 0, stream>>>(hsb, wl2s, bl2, xlb, NN, 1024, 2048);
  gemm_mfma<<<dim3(1024 / 128, NN / 128), 256, 0, stream>>>(hsb, wr2s, br2, xrb, NN, 1024, 2048);
  hipMemsetAsync(w + z2, 0, z2e - z2, stream);
  k_edge_logits<4, 1024><<<ET / 32, 256, 0, stream>>>(ebb, ei, ea, eab, xlb, xrb, We2, att2, Lb);
  k_segmax<4><<<ET * 4 / 256, 256, 0, stream>>>(Lb, dpb, maxb);
  k_exp_den<4><<<ET * 4 / 256, 256, 0, stream>>>(Lb, dpb, maxb, denb);
  k_invden<<<NN * 4 / 256, 256, 0, stream>>>(denb);
  k_aggregate<4, 1024, false><<<NN, 256, 0, stream>>>(ipb, ebb, ei, Lb, denb, xlb, bias2,
                                                      h2b, nullptr);

  // ---- pool + MLP ----
  k_gstart<<<1, 64, 0, stream>>>(batch, gsb);
  k_pool2<<<dim3(4, GG), 256, 0, stream>>>(h2b, gsb, poolb);
  gemm_nt<<<dim3(512 / 64, 1), 256, 0, stream>>>(poolb, W1, b1, m1b, GG, 512, 1024, 1);
  gemm_nt<<<dim3(256 / 64, 1), 256, 0, stream>>>(m1b, W2, b2, m2b, GG, 256, 512, 1);
  k_head<<<1, 64, 0, stream>>>(m2b, W3, b3, out);
}

// Round 9
// 1017.788 us; speedup vs baseline: 1.9879x; 1.3050x over previous
//
#include <hip/hip_runtime.h>
#include <math.h>

// ---------------- problem constants ----------------
constexpr int NN = 8192;          // nodes
constexpr int EE = 65536;         // original edges
constexpr int ET = EE + NN;       // edges incl self loops = 73728
constexpr int GG = 64;            // graphs
constexpr float SLOPE = 0.2f;

using bf16 = __bf16;
using bf16x8 = __bf16 __attribute__((ext_vector_type(8)));
using bf16x4 = __bf16 __attribute__((ext_vector_type(4)));
using f32x4v = float __attribute__((ext_vector_type(4)));

// ---------------- helpers ----------------
__device__ __forceinline__ unsigned enc_f(float f) {
  unsigned u = __float_as_uint(f);
  return (u & 0x80000000u) ? ~u : (u | 0x80000000u);
}
__device__ __forceinline__ float dec_f(unsigned e) {
  return (e & 0x80000000u) ? __uint_as_float(e & 0x7FFFFFFFu) : __uint_as_float(~e);
}

// async global->LDS, 16B per lane. LDS dest must be WAVE-UNIFORM base (+lane*16 by HW).
__device__ __forceinline__ void gl2lds16(const void* g, void* l) {
  __builtin_amdgcn_global_load_lds(
      (const __attribute__((address_space(1))) void*)g,
      (__attribute__((address_space(3))) void*)l, 16, 0, 0);
}

// ---------------- CSR build (edges sorted by dst) ----------------
__global__ __launch_bounds__(256) void k_counts(const int* __restrict__ ei,
                                                int* __restrict__ cnt) {
  int e = blockIdx.x * 256 + threadIdx.x;        // ET
  int d = (e < EE) ? ei[EE + e] : (e - EE);
  atomicAdd(cnt + d, 1);
}

__global__ __launch_bounds__(1024) void k_scan(const int* __restrict__ cnt,
                                               int* __restrict__ indptr,
                                               int* __restrict__ wpos) {
  __shared__ int sums[1024];
  int t = threadIdx.x;
  int local[8];
  int s = 0;
  #pragma unroll
  for (int i = 0; i < 8; ++i) { local[i] = s; s += cnt[t * 8 + i]; }
  sums[t] = s;
  __syncthreads();
  for (int off = 1; off < 1024; off <<= 1) {
    int v = (t >= off) ? sums[t - off] : 0;
    __syncthreads();
    sums[t] += v;
    __syncthreads();
  }
  int base = (t == 0) ? 0 : sums[t - 1];
  #pragma unroll
  for (int i = 0; i < 8; ++i) {
    int v = base + local[i];
    indptr[t * 8 + i] = v;
    wpos[t * 8 + i] = v;
  }
  if (t == 1023) indptr[NN] = sums[1023];
}

__global__ __launch_bounds__(256) void k_fill(const int* __restrict__ ei,
                                              int* __restrict__ wpos,
                                              int* __restrict__ ebyd,
                                              int* __restrict__ dstp) {
  int e = blockIdx.x * 256 + threadIdx.x;        // ET
  int d = (e < EE) ? ei[EE + e] : (e - EE);
  int idx = atomicAdd(wpos + d, 1);
  ebyd[idx] = e;
  dstp[idx] = d;
}

// self-loop edge attr = mean of incoming original edge attrs (atomic-free, via CSR)
__global__ __launch_bounds__(256) void k_loopea(const int* __restrict__ ip,
                                                const int* __restrict__ ebyd,
                                                const float* __restrict__ ea,
                                                float* __restrict__ easum) {
  int node = blockIdx.x * 8 + (threadIdx.x >> 5);
  int k = threadIdx.x & 31;
  float acc = 0.0f, deg = 0.0f;
  int p0 = ip[node], p1 = ip[node + 1];
  for (int p = p0; p < p1; ++p) {
    int e = ebyd[p];
    if (e < EE) { acc += ea[(size_t)e * 32 + k]; deg += 1.0f; }
  }
  easum[(size_t)node * 32 + k] = acc / fmaxf(deg, 1.0f);
}

// ---------------- fp32 -> split bf16 [hi | lo], row-major [M][2K] ----------------
__global__ __launch_bounds__(256) void k_split(const float* __restrict__ in,
                                               bf16* __restrict__ out,
                                               int K, int total4) {
  int i = blockIdx.x * 256 + threadIdx.x;
  if (i >= total4) return;
  int K4 = K >> 2;
  int m = i / K4, k4 = (i - m * K4) << 2;
  float4 v = *reinterpret_cast<const float4*>(in + (size_t)m * K + k4);
  float vv[4] = {v.x, v.y, v.z, v.w};
  bf16x4 hi, lo;
  #pragma unroll
  for (int u = 0; u < 4; ++u) {
    bf16 h = (bf16)vv[u];
    hi[u] = h;
    lo[u] = (bf16)(vv[u] - (float)h);
  }
  *reinterpret_cast<bf16x4*>(out + (size_t)m * 2 * K + k4) = hi;
  *reinterpret_cast<bf16x4*>(out + (size_t)m * 2 * K + K + k4) = lo;
}

// ---------------- split-bf16 MFMA GEMM (m97 structure) ----------------
__global__ __launch_bounds__(256) void gemm_mfma(
    const bf16* __restrict__ A, const bf16* __restrict__ B,
    const float* __restrict__ bias, float* __restrict__ C,
    int M, int Nc, int Ko) {
  __shared__ __attribute__((aligned(16))) bf16 As[128][32];
  __shared__ __attribute__((aligned(16))) bf16 Bs[128][32];
  const int tid = threadIdx.x;
  const int wave = tid >> 6, lane = tid & 63;
  const int wr = wave >> 1, wc = wave & 1;
  const int l16 = lane & 15, lk = lane >> 4;
  const int m0 = blockIdx.y * 128, n0 = blockIdx.x * 128;
  const int ld = 2 * Ko;
  const int r0 = tid >> 2, c8 = (tid & 3) * 8;

  f32x4v acc[4][4] = {};
  for (int k0 = 0; k0 < 3 * Ko; k0 += 32) {
    int ka = (k0 < Ko) ? k0 : k0 - Ko;          // A: hi, hi, lo
    int kb = (k0 < 2 * Ko) ? k0 : k0 - 2 * Ko;  // B: hi, lo, hi
    #pragma unroll
    for (int i = 0; i < 2; ++i) {
      int row = i * 64 + r0;
      bf16* abase = &As[0][0] + ((size_t)(i * 256 + wave * 64)) * 8;
      bf16* bbase = &Bs[0][0] + ((size_t)(i * 256 + wave * 64)) * 8;
      gl2lds16(A + (size_t)(m0 + row) * ld + ka + c8, abase);
      gl2lds16(B + (size_t)(n0 + row) * ld + kb + c8, bbase);
    }
    __syncthreads();
    bf16x8 af[4], bfr[4];
    #pragma unroll
    for (int mi = 0; mi < 4; ++mi)
      af[mi] = *reinterpret_cast<const bf16x8*>(&As[wr * 64 + mi * 16 + l16][lk * 8]);
    #pragma unroll
    for (int ni = 0; ni < 4; ++ni)
      bfr[ni] = *reinterpret_cast<const bf16x8*>(&Bs[wc * 64 + ni * 16 + l16][lk * 8]);
    #pragma unroll
    for (int mi = 0; mi < 4; ++mi)
      #pragma unroll
      for (int ni = 0; ni < 4; ++ni)
        acc[mi][ni] = __builtin_amdgcn_mfma_f32_16x16x32_bf16(af[mi], bfr[ni],
                                                              acc[mi][ni], 0, 0, 0);
    __syncthreads();
  }
  #pragma unroll
  for (int mi = 0; mi < 4; ++mi) {
    #pragma unroll
    for (int ni = 0; ni < 4; ++ni) {
      int col = n0 + wc * 64 + ni * 16 + l16;
      float bv = bias ? bias[col] : 0.0f;
      #pragma unroll
      for (int j = 0; j < 4; ++j) {
        int row = m0 + wr * 64 + mi * 16 + lk * 4 + j;
        C[(size_t)row * Nc + col] = acc[mi][ni][j] + bv;
      }
    }
  }
}

// ---------------- fp32 GEMM (tiny MLP head only) ----------------
__global__ __launch_bounds__(256) void gemm_nt(
    const float* __restrict__ A, const float* __restrict__ Bm,
    const float* __restrict__ bias, float* __restrict__ Cm,
    int M, int Nc, int K, int act) {
  __shared__ float As[16][68];
  __shared__ float Bs[16][68];
  const int tid = threadIdx.x;
  const int tx = tid & 15, ty = tid >> 4;
  const int m0 = blockIdx.y * 64, n0 = blockIdx.x * 64;
  float acc[4][4] = {};
  for (int k0 = 0; k0 < K; k0 += 16) {
    int r = tid >> 2;
    int c4 = (tid & 3) * 4;
    float4 va = *reinterpret_cast<const float4*>(A + (size_t)(m0 + r) * K + k0 + c4);
    float4 vb = *reinterpret_cast<const float4*>(Bm + (size_t)(n0 + r) * K + k0 + c4);
    As[c4 + 0][r] = va.x; As[c4 + 1][r] = va.y; As[c4 + 2][r] = va.z; As[c4 + 3][r] = va.w;
    Bs[c4 + 0][r] = vb.x; Bs[c4 + 1][r] = vb.y; Bs[c4 + 2][r] = vb.z; Bs[c4 + 3][r] = vb.w;
    __syncthreads();
    #pragma unroll
    for (int k = 0; k < 16; ++k) {
      float a[4], b[4];
      #pragma unroll
      for (int i = 0; i < 4; ++i) a[i] = As[k][ty * 4 + i];
      #pragma unroll
      for (int j = 0; j < 4; ++j) b[j] = Bs[k][tx * 4 + j];
      #pragma unroll
      for (int i = 0; i < 4; ++i)
        #pragma unroll
        for (int j = 0; j < 4; ++j) acc[i][j] = fmaf(a[i], b[j], acc[i][j]);
    }
    __syncthreads();
  }
  #pragma unroll
  for (int i = 0; i < 4; ++i) {
    int m = m0 + ty * 4 + i;
    #pragma unroll
    for (int j = 0; j < 4; ++j) {
      int n = n0 + tx * 4 + j;
      float v = acc[i][j] + (bias ? bias[n] : 0.0f);
      if (act == 1) v = fmaxf(v, 0.0f);
      Cm[(size_t)m * Nc + n] = v;
    }
  }
}

// ---------------- per-edge logit pass, MFMA ee ----------------
// Block: 64 edges (dst-sorted), 4 waves x 16 edges. Per 64-chan chunk:
// ee tile via 3-term split-bf16 mfma_16x16x32 (ea[hi|lo] x We[hi|lo]),
// then epilogue on C-layout: chan = lane&15 (coalesced), edge = (lane>>4)*4+j.
template <int H, int F>
__global__ __launch_bounds__(256) void k_edge_logits_mfma(
    const int* __restrict__ ebyd, const int* __restrict__ ei,
    const float* __restrict__ edge_attr, const float* __restrict__ loop_ea,
    const float* __restrict__ xl, const float* __restrict__ xr,
    const bf16* __restrict__ Wes,   // [F][64] split hi|lo
    const float* __restrict__ att,  // [F]
    float* __restrict__ L) {
  __shared__ __attribute__((aligned(16))) bf16 ea_s[64][72];  // 144B row: 16B-aligned, 2-way bank alias (free)
  __shared__ __attribute__((aligned(16))) bf16 we_s[64][72];
  __shared__ int ss[64], dd[64];
  const int tid = threadIdx.x;
  const int wave = tid >> 6, lane = tid & 63;
  const int l16 = lane & 15, lk = lane >> 4;
  const int pbase = blockIdx.x * 64;

  if (tid < 64) {
    int e = ebyd[pbase + tid];
    int s, d;
    if (e < EE) { s = ei[e]; d = ei[EE + e]; }
    else { s = d = e - EE; }
    ss[tid] = s; dd[tid] = d;
  }
  {
    int edge = tid >> 2, a0 = (tid & 3) * 8;
    int e = ebyd[pbase + edge];
    const float* srcp = (e < EE) ? (edge_attr + (size_t)e * 32 + a0)
                                 : (loop_ea + (size_t)(e - EE) * 32 + a0);
    float4 v0 = *reinterpret_cast<const float4*>(srcp);
    float4 v1 = *reinterpret_cast<const float4*>(srcp + 4);
    float vv[8] = {v0.x, v0.y, v0.z, v0.w, v1.x, v1.y, v1.z, v1.w};
    bf16x8 hi, lo;
    #pragma unroll
    for (int u = 0; u < 8; ++u) {
      bf16 h = (bf16)vv[u];
      hi[u] = h; lo[u] = (bf16)(vv[u] - (float)h);
    }
    *reinterpret_cast<bf16x8*>(&ea_s[edge][a0]) = hi;
    *reinterpret_cast<bf16x8*>(&ea_s[edge][32 + a0]) = lo;
  }
  __syncthreads();

  // hoist A-frags (constant across chunks) + per-lane row pointers
  bf16x8 af_hi = *reinterpret_cast<const bf16x8*>(&ea_s[wave * 16 + l16][lk * 8]);
  bf16x8 af_lo = *reinterpret_cast<const bf16x8*>(&ea_s[wave * 16 + l16][32 + lk * 8]);
  const float* xlp[4];
  const float* xrp[4];
  #pragma unroll
  for (int j = 0; j < 4; ++j) {
    int es = wave * 16 + lk * 4 + j;
    xlp[j] = xl + (size_t)ss[es] * F;
    xrp[j] = xr + (size_t)dd[es] * F;
  }

  float lg[4] = {};
  for (int jc = 0; jc < F; jc += 64) {
    __syncthreads();               // protect we_s from previous chunk's reads
    {
      int row = tid >> 2, c0 = (tid & 3) * 16;
      const bf16* gp = Wes + (size_t)(jc + row) * 64 + c0;
      bf16x8 w0 = *reinterpret_cast<const bf16x8*>(gp);
      bf16x8 w1 = *reinterpret_cast<const bf16x8*>(gp + 8);
      *reinterpret_cast<bf16x8*>(&we_s[row][c0]) = w0;
      *reinterpret_cast<bf16x8*>(&we_s[row][c0 + 8]) = w1;
    }
    __syncthreads();
    #pragma unroll
    for (int ni = 0; ni < 4; ++ni) {
      bf16x8 bh = *reinterpret_cast<const bf16x8*>(&we_s[ni * 16 + l16][lk * 8]);
      bf16x8 bl = *reinterpret_cast<const bf16x8*>(&we_s[ni * 16 + l16][32 + lk * 8]);
      f32x4v acc = {};
      acc = __builtin_amdgcn_mfma_f32_16x16x32_bf16(af_hi, bh, acc, 0, 0, 0);
      acc = __builtin_amdgcn_mfma_f32_16x16x32_bf16(af_lo, bh, acc, 0, 0, 0);
      acc = __builtin_amdgcn_mfma_f32_16x16x32_bf16(af_hi, bl, acc, 0, 0, 0);
      int chan = jc + ni * 16 + l16;
      float av = att[chan];
      #pragma unroll
      for (int j = 0; j < 4; ++j) {
        float m = xlp[j][chan] + xrp[j][chan] + acc[j];
        m = (m > 0.0f) ? m : (SLOPE * m);
        lg[j] = fmaf(m, av, lg[j]);
      }
    }
    if ((jc & 255) == 192) {       // finished a 256-chan head
      int h = jc >> 8;
      #pragma unroll
      for (int j = 0; j < 4; ++j) {
        float r = lg[j];
        r += __shfl_xor(r, 1);
        r += __shfl_xor(r, 2);
        r += __shfl_xor(r, 4);
        r += __shfl_xor(r, 8);
        if (l16 == 0) L[(size_t)(pbase + wave * 16 + lk * 4 + j) * H + h] = r;
        lg[j] = 0.0f;
      }
    }
  }
}

// ---------------- segment softmax ----------------
template <int H>
__global__ __launch_bounds__(256) void k_segmax(const float* __restrict__ L,
                                                const int* __restrict__ dstp,
                                                unsigned* __restrict__ mx) {
  int i = blockIdx.x * 256 + threadIdx.x;
  int p = i / H, h = i - p * H;
  atomicMax(mx + (size_t)dstp[p] * H + h, enc_f(L[i]));
}

template <int H>
__global__ __launch_bounds__(256) void k_exp_den(float* __restrict__ L,
                                                 const int* __restrict__ dstp,
                                                 const unsigned* __restrict__ mx,
                                                 float* __restrict__ den) {
  int i = blockIdx.x * 256 + threadIdx.x;
  int p = i / H, h = i - p * H;
  int d = dstp[p];
  float ex = expf(L[i] - dec_f(mx[(size_t)d * H + h]));
  L[i] = ex;
  atomicAdd(den + (size_t)d * H + h, ex);
}

__global__ __launch_bounds__(256) void k_invden(float* __restrict__ den) {
  int i = blockIdx.x * 256 + threadIdx.x;
  den[i] = 1.0f / den[i];
}

// ---------------- alpha-weighted aggregation (CSR, atomic-free) ----------------
template <int H, int F, bool SPLIT>
__global__ __launch_bounds__(256) void k_aggregate(
    const int* __restrict__ indptr, const int* __restrict__ ebyd,
    const int* __restrict__ ei, const float* __restrict__ L,
    const float* __restrict__ invden, const float* __restrict__ xl,
    const float* __restrict__ bias, float* __restrict__ out,
    bf16* __restrict__ outs) {
  constexpr int CPE = F / 256;
  const int n = blockIdx.x;
  const int tid = threadIdx.x;
  const int j0 = tid * CPE;
  const int h = j0 >> 8;
  const float invd = invden[(size_t)n * H + h];
  float acc[CPE] = {};
  const int p0 = indptr[n], p1 = indptr[n + 1];
  for (int p = p0; p < p1; ++p) {
    int e = ebyd[p];
    int s = (e < EE) ? ei[e] : (e - EE);
    float a = L[(size_t)p * H + h] * invd;
    const float* row = xl + (size_t)s * F + j0;
    #pragma unroll
    for (int q = 0; q < CPE; q += 4) {
      float4 v = *reinterpret_cast<const float4*>(row + q);
      acc[q + 0] = fmaf(a, v.x, acc[q + 0]);
      acc[q + 1] = fmaf(a, v.y, acc[q + 1]);
      acc[q + 2] = fmaf(a, v.z, acc[q + 2]);
      acc[q + 3] = fmaf(a, v.w, acc[q + 3]);
    }
  }
  #pragma unroll
  for (int q = 0; q < CPE; ++q) {
    float v = acc[q] + bias[j0 + q];
    if (SPLIT) {
      v = fmaxf(v, 0.0f);
      bf16 hi = (bf16)v;
      outs[(size_t)n * (2 * F) + j0 + q] = hi;
      outs[(size_t)n * (2 * F) + F + j0 + q] = (bf16)(v - (float)hi);
    } else {
      out[(size_t)n * F + j0 + q] = v;
    }
  }
}

// ---------------- pooling (batch sorted -> segmented mean) ----------------
__global__ __launch_bounds__(64) void k_gstart(const int* __restrict__ batch,
                                               int* __restrict__ gstart) {
  int g = threadIdx.x;
  int lo = 0, hi = NN;
  while (lo < hi) { int mid = (lo + hi) >> 1; if (batch[mid] < g) lo = mid + 1; else hi = mid; }
  gstart[g] = lo;
  if (g == 63) gstart[64] = NN;
}

__global__ __launch_bounds__(256) void k_pool2(const float* __restrict__ h2,
                                               const int* __restrict__ gstart,
                                               float* __restrict__ pooled) {
  int g = blockIdx.y;
  int j = blockIdx.x * 256 + threadIdx.x;
  int s = gstart[g], e2 = gstart[g + 1];
  float acc = 0.0f;
  for (int n = s; n < e2; ++n) acc += h2[(size_t)n * 1024 + j];
  pooled[(size_t)g * 1024 + j] = acc / fmaxf((float)(e2 - s), 1.0f);
}

__global__ __launch_bounds__(64) void k_head(const float* __restrict__ m2,
                                             const float* __restrict__ W3,
                                             const float* __restrict__ b3,
                                             float* __restrict__ out) {
  int g = threadIdx.x;
  float a = 0.0f;
  for (int k = 0; k < 256; ++k) a = fmaf(m2[(size_t)g * 256 + k], W3[k], a);
  a += b3[0];
  out[g] = 1.0f / (1.0f + expf(-a));
}

// ---------------- launch ----------------
extern "C" void kernel_launch(void* const* d_in, const int* in_sizes, int n_in,
                              void* d_out, int out_size, void* d_ws, size_t ws_size,
                              hipStream_t stream) {
  const float* x    = (const float*)d_in[0];
  const int*   ei   = (const int*)d_in[1];
  const float* ea   = (const float*)d_in[2];
  const int*   batch= (const int*)d_in[3];
  const float* Wl1  = (const float*)d_in[4];
  const float* bl1  = (const float*)d_in[5];
  const float* Wr1  = (const float*)d_in[6];
  const float* br1  = (const float*)d_in[7];
  const float* We1  = (const float*)d_in[8];
  const float* att1 = (const float*)d_in[9];
  const float* bias1= (const float*)d_in[10];
  const float* Wl2  = (const float*)d_in[11];
  const float* bl2  = (const float*)d_in[12];
  const float* Wr2  = (const float*)d_in[13];
  const float* br2  = (const float*)d_in[14];
  const float* We2  = (const float*)d_in[15];
  const float* att2 = (const float*)d_in[16];
  const float* bias2= (const float*)d_in[17];
  const float* W1   = (const float*)d_in[18];
  const float* b1   = (const float*)d_in[19];
  const float* W2   = (const float*)d_in[20];
  const float* b2   = (const float*)d_in[21];
  const float* W3   = (const float*)d_in[22];
  const float* b3   = (const float*)d_in[23];
  float* out = (float*)d_out;

  char* w = (char*)d_ws;
  size_t off = 0;
  auto take = [&](size_t b) { size_t r = off; off = (off + b + 255) & ~(size_t)255; return r; };

  size_t xl_off  = take((size_t)NN * 2048 * 4);   // layer1 xl; layer2 xl in [0,32MB), h2 in [32,64MB)
  size_t xr_off  = take((size_t)NN * 2048 * 4);
  size_t hs_off  = take((size_t)NN * 4096 * 2);   // split bf16 of relu(h1)
  size_t xs_off  = take((size_t)NN * 128 * 2);    // split bf16 of x
  size_t wl1s_off= take((size_t)2048 * 128 * 2);
  size_t wr1s_off= take((size_t)2048 * 128 * 2);
  size_t wl2s_off= take((size_t)1024 * 4096 * 2);
  size_t wr2s_off= take((size_t)1024 * 4096 * 2);
  size_t we1s_off= take((size_t)2048 * 64 * 2);
  size_t we2s_off= take((size_t)1024 * 64 * 2);
  size_t L_off   = take((size_t)ET * 8 * 4);
  size_t z1      = off;                           // ---- zero zone: cnt | den | max ----
  size_t cnt_off = take((size_t)NN * 4);
  size_t z2      = off;                           // ---- re-zeroed before layer 2 ----
  size_t den_off = take((size_t)NN * 8 * 4);
  size_t max_off = take((size_t)NN * 8 * 4);
  size_t z2e     = off;
  size_t ea_off  = take((size_t)NN * 32 * 4);
  size_t ip_off  = take((size_t)(NN + 1) * 4);
  size_t wp_off  = take((size_t)NN * 4);
  size_t eb_off  = take((size_t)ET * 4);
  size_t dp_off  = take((size_t)ET * 4);
  size_t gs_off  = take((size_t)65 * 4);
  size_t pool_off= take((size_t)GG * 1024 * 4);
  size_t m1_off  = take((size_t)GG * 512 * 4);
  size_t m2_off  = take((size_t)GG * 256 * 4);
  (void)ws_size; (void)n_in; (void)in_sizes; (void)out_size;

  float*    xlb   = (float*)(w + xl_off);
  float*    xrb   = (float*)(w + xr_off);
  float*    h2b   = (float*)(w + xl_off) + (size_t)NN * 1024;
  bf16*     hsb   = (bf16*)(w + hs_off);
  bf16*     xsb   = (bf16*)(w + xs_off);
  bf16*     wl1s  = (bf16*)(w + wl1s_off);
  bf16*     wr1s  = (bf16*)(w + wr1s_off);
  bf16*     wl2s  = (bf16*)(w + wl2s_off);
  bf16*     wr2s  = (bf16*)(w + wr2s_off);
  bf16*     we1s  = (bf16*)(w + we1s_off);
  bf16*     we2s  = (bf16*)(w + we2s_off);
  float*    Lb    = (float*)(w + L_off);
  int*      cntb  = (int*)(w + cnt_off);
  float*    denb  = (float*)(w + den_off);
  unsigned* maxb  = (unsigned*)(w + max_off);
  float*    eab   = (float*)(w + ea_off);
  int*      ipb   = (int*)(w + ip_off);
  int*      wpb   = (int*)(w + wp_off);
  int*      ebb   = (int*)(w + eb_off);
  int*      dpb   = (int*)(w + dp_off);
  int*      gsb   = (int*)(w + gs_off);
  float*    poolb = (float*)(w + pool_off);
  float*    m1b   = (float*)(w + m1_off);
  float*    m2b   = (float*)(w + m2_off);

  hipMemsetAsync(w + z1, 0, z2e - z1, stream);

  // CSR + self-loop edge attrs
  k_counts<<<ET / 256, 256, 0, stream>>>(ei, cntb);
  k_scan<<<1, 1024, 0, stream>>>(cntb, ipb, wpb);
  k_fill<<<ET / 256, 256, 0, stream>>>(ei, wpb, ebb, dpb);
  k_loopea<<<NN / 8, 256, 0, stream>>>(ipb, ebb, ea, eab);

  // split conversions
  k_split<<<(NN * 64 / 4 + 255) / 256, 256, 0, stream>>>(x, xsb, 64, NN * 64 / 4);
  k_split<<<(2048 * 64 / 4 + 255) / 256, 256, 0, stream>>>(Wl1, wl1s, 64, 2048 * 64 / 4);
  k_split<<<(2048 * 64 / 4 + 255) / 256, 256, 0, stream>>>(Wr1, wr1s, 64, 2048 * 64 / 4);
  k_split<<<(1024 * 2048 / 4 + 255) / 256, 256, 0, stream>>>(Wl2, wl2s, 2048, 1024 * 2048 / 4);
  k_split<<<(1024 * 2048 / 4 + 255) / 256, 256, 0, stream>>>(Wr2, wr2s, 2048, 1024 * 2048 / 4);
  k_split<<<(2048 * 32 / 4 + 255) / 256, 256, 0, stream>>>(We1, we1s, 32, 2048 * 32 / 4);
  k_split<<<(1024 * 32 / 4 + 255) / 256, 256, 0, stream>>>(We2, we2s, 32, 1024 * 32 / 4);

  // ---- layer 1 (H=8, F=2048) ----
  gemm_mfma<<<dim3(2048 / 128, NN / 128), 256, 0, stream>>>(xsb, wl1s, bl1, xlb, NN, 2048, 64);
  gemm_mfma<<<dim3(2048 / 128, NN / 128), 256, 0, stream>>>(xsb, wr1s, br1, xrb, NN, 2048, 64);
  k_edge_logits_mfma<8, 2048><<<ET / 64, 256, 0, stream>>>(ebb, ei, ea, eab, xlb, xrb,
                                                           we1s, att1, Lb);
  k_segmax<8><<<ET * 8 / 256, 256, 0, stream>>>(Lb, dpb, maxb);
  k_exp_den<8><<<ET * 8 / 256, 256, 0, stream>>>(Lb, dpb, maxb, denb);
  k_invden<<<NN * 8 / 256, 256, 0, stream>>>(denb);
  k_aggregate<8, 2048, true><<<NN, 256, 0, stream>>>(ipb, ebb, ei, Lb, denb, xlb, bias1,
                                                     nullptr, hsb);

  // ---- layer 2 (H=4, F=1024) ----
  gemm_mfma<<<dim3(1024 / 128, NN / 128), 256, 0, stream>>>(hsb, wl2s, bl2, xlb, NN, 1024, 2048);
  gemm_mfma<<<dim3(1024 / 128, NN / 128), 256, 0, stream>>>(hsb, wr2s, br2, xrb, NN, 1024, 2048);
  hipMemsetAsync(w + z2, 0, z2e - z2, stream);
  k_edge_logits_mfma<4, 1024><<<ET / 64, 256, 0, stream>>>(ebb, ei, ea, eab, xlb, xrb,
                                                           we2s, att2, Lb);
  k_segmax<4><<<ET * 4 / 256, 256, 0, stream>>>(Lb, dpb, maxb);
  k_exp_den<4><<<ET * 4 / 256, 256, 0, stream>>>(Lb, dpb, maxb, denb);
  k_invden<<<NN * 4 / 256, 256, 0, stream>>>(denb);
  k_aggregate<4, 1024, false><<<NN, 256, 0, stream>>>(ipb, ebb, ei, Lb, denb, xlb, bias2,
                                                      h2b, nullptr);

  // ---- pool + MLP ----
  k_gstart<<<1, 64, 0, stream>>>(batch, gsb);
  k_pool2<<<dim3(4, GG), 256, 0, stream>>>(h2b, gsb, poolb);
  gemm_nt<<<dim3(512 / 64, 1), 256, 0, stream>>>(poolb, W1, b1, m1b, GG, 512, 1024, 1);
  gemm_nt<<<dim3(256 / 64, 1), 256, 0, stream>>>(m1b, W2, b2, m2b, GG, 256, 512, 1);
  k_head<<<1, 64, 0, stream>>>(m2b, W3, b3, out);
}

// Round 10
// 993.781 us; speedup vs baseline: 2.0360x; 1.0242x over previous
//
#include <hip/hip_runtime.h>
#include <math.h>

// ---------------- problem constants ----------------
constexpr int NN = 8192;          // nodes
constexpr int EE = 65536;         // original edges
constexpr int ET = EE + NN;       // edges incl self loops = 73728
constexpr int GG = 64;            // graphs
constexpr float SLOPE = 0.2f;

using bf16 = __bf16;
using bf16x8 = __bf16 __attribute__((ext_vector_type(8)));
using bf16x4 = __bf16 __attribute__((ext_vector_type(4)));
using f32x4v = float __attribute__((ext_vector_type(4)));

// ---------------- helpers ----------------
__device__ __forceinline__ unsigned enc_f(float f) {
  unsigned u = __float_as_uint(f);
  return (u & 0x80000000u) ? ~u : (u | 0x80000000u);
}
__device__ __forceinline__ float dec_f(unsigned e) {
  return (e & 0x80000000u) ? __uint_as_float(e & 0x7FFFFFFFu) : __uint_as_float(~e);
}

// async global->LDS, 16B per lane. LDS dest must be WAVE-UNIFORM base (+lane*16 by HW).
__device__ __forceinline__ void gl2lds16(const void* g, void* l) {
  __builtin_amdgcn_global_load_lds(
      (const __attribute__((address_space(1))) void*)g,
      (__attribute__((address_space(3))) void*)l, 16, 0, 0);
}

// ---------------- CSR build (edges sorted by dst) ----------------
__global__ __launch_bounds__(256) void k_counts(const int* __restrict__ ei,
                                                int* __restrict__ cnt) {
  int e = blockIdx.x * 256 + threadIdx.x;        // ET
  int d = (e < EE) ? ei[EE + e] : (e - EE);
  atomicAdd(cnt + d, 1);
}

__global__ __launch_bounds__(1024) void k_scan(const int* __restrict__ cnt,
                                               int* __restrict__ indptr,
                                               int* __restrict__ wpos) {
  __shared__ int sums[1024];
  int t = threadIdx.x;
  int local[8];
  int s = 0;
  #pragma unroll
  for (int i = 0; i < 8; ++i) { local[i] = s; s += cnt[t * 8 + i]; }
  sums[t] = s;
  __syncthreads();
  for (int off = 1; off < 1024; off <<= 1) {
    int v = (t >= off) ? sums[t - off] : 0;
    __syncthreads();
    sums[t] += v;
    __syncthreads();
  }
  int base = (t == 0) ? 0 : sums[t - 1];
  #pragma unroll
  for (int i = 0; i < 8; ++i) {
    int v = base + local[i];
    indptr[t * 8 + i] = v;
    wpos[t * 8 + i] = v;
  }
  if (t == 1023) indptr[NN] = sums[1023];
}

__global__ __launch_bounds__(256) void k_fill(const int* __restrict__ ei,
                                              int* __restrict__ wpos,
                                              int* __restrict__ ebyd,
                                              int* __restrict__ dstp) {
  int e = blockIdx.x * 256 + threadIdx.x;        // ET
  int d = (e < EE) ? ei[EE + e] : (e - EE);
  int idx = atomicAdd(wpos + d, 1);
  ebyd[idx] = e;
  dstp[idx] = d;
}

// self-loop edge attr = mean of incoming original edge attrs (atomic-free, via CSR)
__global__ __launch_bounds__(256) void k_loopea(const int* __restrict__ ip,
                                                const int* __restrict__ ebyd,
                                                const float* __restrict__ ea,
                                                float* __restrict__ easum) {
  int node = blockIdx.x * 8 + (threadIdx.x >> 5);
  int k = threadIdx.x & 31;
  float acc = 0.0f, deg = 0.0f;
  int p0 = ip[node], p1 = ip[node + 1];
  for (int p = p0; p < p1; ++p) {
    int e = ebyd[p];
    if (e < EE) { acc += ea[(size_t)e * 32 + k]; deg += 1.0f; }
  }
  easum[(size_t)node * 32 + k] = acc / fmaxf(deg, 1.0f);
}

// ---------------- fp32 -> split bf16 [hi | lo], row-major [M][2K] ----------------
__global__ __launch_bounds__(256) void k_split(const float* __restrict__ in,
                                               bf16* __restrict__ out,
                                               int K, int total4) {
  int i = blockIdx.x * 256 + threadIdx.x;
  if (i >= total4) return;
  int K4 = K >> 2;
  int m = i / K4, k4 = (i - m * K4) << 2;
  float4 v = *reinterpret_cast<const float4*>(in + (size_t)m * K + k4);
  float vv[4] = {v.x, v.y, v.z, v.w};
  bf16x4 hi, lo;
  #pragma unroll
  for (int u = 0; u < 4; ++u) {
    bf16 h = (bf16)vv[u];
    hi[u] = h;
    lo[u] = (bf16)(vv[u] - (float)h);
  }
  *reinterpret_cast<bf16x4*>(out + (size_t)m * 2 * K + k4) = hi;
  *reinterpret_cast<bf16x4*>(out + (size_t)m * 2 * K + K + k4) = lo;
}

// ---------------- fused dual-B split-bf16 MFMA GEMM ----------------
// Computes C1 = A@B1^T + bias1 AND C2 = A@B2^T + bias2 in one dispatch so the
// A panel is fetched once. T1 XCD swizzle (bijective, nwg%8==0) with n-fastest
// decomposition: each XCD owns a contiguous band of m-rows for ALL n-tiles of
// both B matrices -> A rows hit one XCD's L2 only, B L3-served across XCDs.
// Per-tile math identical to the validated m97-structure kernel (bit-exact).
__global__ __launch_bounds__(256) void gemm_dual(
    const bf16* __restrict__ A, const bf16* __restrict__ B1,
    const bf16* __restrict__ B2, const float* __restrict__ bias1,
    const float* __restrict__ bias2, float* __restrict__ C1,
    float* __restrict__ C2, int M, int Nc, int Ko) {
  __shared__ __attribute__((aligned(16))) bf16 As[128][32];
  __shared__ __attribute__((aligned(16))) bf16 Bs[128][32];
  const int tid = threadIdx.x;
  const int wave = tid >> 6, lane = tid & 63;
  const int wr = wave >> 1, wc = wave & 1;
  const int l16 = lane & 15, lk = lane >> 4;

  // ---- swizzled block -> (m-tile, n-tile, which-B) ----
  const int nwg = gridDim.x * gridDim.y;
  const int bid = blockIdx.y * gridDim.x + blockIdx.x;
  const int cpx = nwg >> 3;                    // blocks per XCD (nwg % 8 == 0)
  const int swz = (bid & 7) * cpx + (bid >> 3);
  const int tn2 = swz % gridDim.x;             // n-fastest within XCD band
  const int tm  = swz / gridDim.x;
  const int ntn = gridDim.x >> 1;              // n-tiles per B matrix
  const bool second = tn2 >= ntn;
  const int m0 = tm * 128;
  const int n0 = (second ? tn2 - ntn : tn2) * 128;
  const bf16* B = second ? B2 : B1;
  const float* bias = second ? bias2 : bias1;
  float* C = second ? C2 : C1;

  const int ld = 2 * Ko;
  const int r0 = tid >> 2, c8 = (tid & 3) * 8;

  f32x4v acc[4][4] = {};
  for (int k0 = 0; k0 < 3 * Ko; k0 += 32) {
    int ka = (k0 < Ko) ? k0 : k0 - Ko;          // A: hi, hi, lo
    int kb = (k0 < 2 * Ko) ? k0 : k0 - 2 * Ko;  // B: hi, lo, hi
    #pragma unroll
    for (int i = 0; i < 2; ++i) {
      int row = i * 64 + r0;
      bf16* abase = &As[0][0] + ((size_t)(i * 256 + wave * 64)) * 8;
      bf16* bbase = &Bs[0][0] + ((size_t)(i * 256 + wave * 64)) * 8;
      gl2lds16(A + (size_t)(m0 + row) * ld + ka + c8, abase);
      gl2lds16(B + (size_t)(n0 + row) * ld + kb + c8, bbase);
    }
    __syncthreads();
    bf16x8 af[4], bfr[4];
    #pragma unroll
    for (int mi = 0; mi < 4; ++mi)
      af[mi] = *reinterpret_cast<const bf16x8*>(&As[wr * 64 + mi * 16 + l16][lk * 8]);
    #pragma unroll
    for (int ni = 0; ni < 4; ++ni)
      bfr[ni] = *reinterpret_cast<const bf16x8*>(&Bs[wc * 64 + ni * 16 + l16][lk * 8]);
    #pragma unroll
    for (int mi = 0; mi < 4; ++mi)
      #pragma unroll
      for (int ni = 0; ni < 4; ++ni)
        acc[mi][ni] = __builtin_amdgcn_mfma_f32_16x16x32_bf16(af[mi], bfr[ni],
                                                              acc[mi][ni], 0, 0, 0);
    __syncthreads();
  }
  // C/D layout (m89-verified): col = lane&15, row = (lane>>4)*4 + reg
  #pragma unroll
  for (int mi = 0; mi < 4; ++mi) {
    #pragma unroll
    for (int ni = 0; ni < 4; ++ni) {
      int col = n0 + wc * 64 + ni * 16 + l16;
      float bv = bias ? bias[col] : 0.0f;
      #pragma unroll
      for (int j = 0; j < 4; ++j) {
        int row = m0 + wr * 64 + mi * 16 + lk * 4 + j;
        C[(size_t)row * Nc + col] = acc[mi][ni][j] + bv;
      }
    }
  }
}

// ---------------- fp32 GEMM (tiny MLP head only) ----------------
__global__ __launch_bounds__(256) void gemm_nt(
    const float* __restrict__ A, const float* __restrict__ Bm,
    const float* __restrict__ bias, float* __restrict__ Cm,
    int M, int Nc, int K, int act) {
  __shared__ float As[16][68];
  __shared__ float Bs[16][68];
  const int tid = threadIdx.x;
  const int tx = tid & 15, ty = tid >> 4;
  const int m0 = blockIdx.y * 64, n0 = blockIdx.x * 64;
  float acc[4][4] = {};
  for (int k0 = 0; k0 < K; k0 += 16) {
    int r = tid >> 2;
    int c4 = (tid & 3) * 4;
    float4 va = *reinterpret_cast<const float4*>(A + (size_t)(m0 + r) * K + k0 + c4);
    float4 vb = *reinterpret_cast<const float4*>(Bm + (size_t)(n0 + r) * K + k0 + c4);
    As[c4 + 0][r] = va.x; As[c4 + 1][r] = va.y; As[c4 + 2][r] = va.z; As[c4 + 3][r] = va.w;
    Bs[c4 + 0][r] = vb.x; Bs[c4 + 1][r] = vb.y; Bs[c4 + 2][r] = vb.z; Bs[c4 + 3][r] = vb.w;
    __syncthreads();
    #pragma unroll
    for (int k = 0; k < 16; ++k) {
      float a[4], b[4];
      #pragma unroll
      for (int i = 0; i < 4; ++i) a[i] = As[k][ty * 4 + i];
      #pragma unroll
      for (int j = 0; j < 4; ++j) b[j] = Bs[k][tx * 4 + j];
      #pragma unroll
      for (int i = 0; i < 4; ++i)
        #pragma unroll
        for (int j = 0; j < 4; ++j) acc[i][j] = fmaf(a[i], b[j], acc[i][j]);
    }
    __syncthreads();
  }
  #pragma unroll
  for (int i = 0; i < 4; ++i) {
    int m = m0 + ty * 4 + i;
    #pragma unroll
    for (int j = 0; j < 4; ++j) {
      int n = n0 + tx * 4 + j;
      float v = acc[i][j] + (bias ? bias[n] : 0.0f);
      if (act == 1) v = fmaxf(v, 0.0f);
      Cm[(size_t)m * Nc + n] = v;
    }
  }
}

// ---------------- per-edge logit pass, MFMA ee ----------------
// Block: 64 edges (dst-sorted), 4 waves x 16 edges. Per 64-chan chunk:
// ee tile via 3-term split-bf16 mfma_16x16x32 (ea[hi|lo] x We[hi|lo]),
// then epilogue on C-layout: chan = lane&15 (coalesced), edge = (lane>>4)*4+j.
template <int H, int F>
__global__ __launch_bounds__(256) void k_edge_logits_mfma(
    const int* __restrict__ ebyd, const int* __restrict__ ei,
    const float* __restrict__ edge_attr, const float* __restrict__ loop_ea,
    const float* __restrict__ xl, const float* __restrict__ xr,
    const bf16* __restrict__ Wes,   // [F][64] split hi|lo
    const float* __restrict__ att,  // [F]
    float* __restrict__ L) {
  __shared__ __attribute__((aligned(16))) bf16 ea_s[64][72];  // 144B row: 16B-aligned, 2-way bank alias (free)
  __shared__ __attribute__((aligned(16))) bf16 we_s[64][72];
  __shared__ int ss[64], dd[64];
  const int tid = threadIdx.x;
  const int wave = tid >> 6, lane = tid & 63;
  const int l16 = lane & 15, lk = lane >> 4;
  const int pbase = blockIdx.x * 64;

  if (tid < 64) {
    int e = ebyd[pbase + tid];
    int s, d;
    if (e < EE) { s = ei[e]; d = ei[EE + e]; }
    else { s = d = e - EE; }
    ss[tid] = s; dd[tid] = d;
  }
  {
    int edge = tid >> 2, a0 = (tid & 3) * 8;
    int e = ebyd[pbase + edge];
    const float* srcp = (e < EE) ? (edge_attr + (size_t)e * 32 + a0)
                                 : (loop_ea + (size_t)(e - EE) * 32 + a0);
    float4 v0 = *reinterpret_cast<const float4*>(srcp);
    float4 v1 = *reinterpret_cast<const float4*>(srcp + 4);
    float vv[8] = {v0.x, v0.y, v0.z, v0.w, v1.x, v1.y, v1.z, v1.w};
    bf16x8 hi, lo;
    #pragma unroll
    for (int u = 0; u < 8; ++u) {
      bf16 h = (bf16)vv[u];
      hi[u] = h; lo[u] = (bf16)(vv[u] - (float)h);
    }
    *reinterpret_cast<bf16x8*>(&ea_s[edge][a0]) = hi;
    *reinterpret_cast<bf16x8*>(&ea_s[edge][32 + a0]) = lo;
  }
  __syncthreads();

  // hoist A-frags (constant across chunks) + per-lane row pointers
  bf16x8 af_hi = *reinterpret_cast<const bf16x8*>(&ea_s[wave * 16 + l16][lk * 8]);
  bf16x8 af_lo = *reinterpret_cast<const bf16x8*>(&ea_s[wave * 16 + l16][32 + lk * 8]);
  const float* xlp[4];
  const float* xrp[4];
  #pragma unroll
  for (int j = 0; j < 4; ++j) {
    int es = wave * 16 + lk * 4 + j;
    xlp[j] = xl + (size_t)ss[es] * F;
    xrp[j] = xr + (size_t)dd[es] * F;
  }

  float lg[4] = {};
  for (int jc = 0; jc < F; jc += 64) {
    __syncthreads();               // protect we_s from previous chunk's reads
    {
      int row = tid >> 2, c0 = (tid & 3) * 16;
      const bf16* gp = Wes + (size_t)(jc + row) * 64 + c0;
      bf16x8 w0 = *reinterpret_cast<const bf16x8*>(gp);
      bf16x8 w1 = *reinterpret_cast<const bf16x8*>(gp + 8);
      *reinterpret_cast<bf16x8*>(&we_s[row][c0]) = w0;
      *reinterpret_cast<bf16x8*>(&we_s[row][c0 + 8]) = w1;
    }
    __syncthreads();
    #pragma unroll
    for (int ni = 0; ni < 4; ++ni) {
      bf16x8 bh = *reinterpret_cast<const bf16x8*>(&we_s[ni * 16 + l16][lk * 8]);
      bf16x8 bl = *reinterpret_cast<const bf16x8*>(&we_s[ni * 16 + l16][32 + lk * 8]);
      f32x4v acc = {};
      acc = __builtin_amdgcn_mfma_f32_16x16x32_bf16(af_hi, bh, acc, 0, 0, 0);
      acc = __builtin_amdgcn_mfma_f32_16x16x32_bf16(af_lo, bh, acc, 0, 0, 0);
      acc = __builtin_amdgcn_mfma_f32_16x16x32_bf16(af_hi, bl, acc, 0, 0, 0);
      int chan = jc + ni * 16 + l16;
      float av = att[chan];
      #pragma unroll
      for (int j = 0; j < 4; ++j) {
        float m = xlp[j][chan] + xrp[j][chan] + acc[j];
        m = (m > 0.0f) ? m : (SLOPE * m);
        lg[j] = fmaf(m, av, lg[j]);
      }
    }
    if ((jc & 255) == 192) {       // finished a 256-chan head
      int h = jc >> 8;
      #pragma unroll
      for (int j = 0; j < 4; ++j) {
        float r = lg[j];
        r += __shfl_xor(r, 1);
        r += __shfl_xor(r, 2);
        r += __shfl_xor(r, 4);
        r += __shfl_xor(r, 8);
        if (l16 == 0) L[(size_t)(pbase + wave * 16 + lk * 4 + j) * H + h] = r;
        lg[j] = 0.0f;
      }
    }
  }
}

// ---------------- segment softmax ----------------
template <int H>
__global__ __launch_bounds__(256) void k_segmax(const float* __restrict__ L,
                                                const int* __restrict__ dstp,
                                                unsigned* __restrict__ mx) {
  int i = blockIdx.x * 256 + threadIdx.x;
  int p = i / H, h = i - p * H;
  atomicMax(mx + (size_t)dstp[p] * H + h, enc_f(L[i]));
}

template <int H>
__global__ __launch_bounds__(256) void k_exp_den(float* __restrict__ L,
                                                 const int* __restrict__ dstp,
                                                 const unsigned* __restrict__ mx,
                                                 float* __restrict__ den) {
  int i = blockIdx.x * 256 + threadIdx.x;
  int p = i / H, h = i - p * H;
  int d = dstp[p];
  float ex = expf(L[i] - dec_f(mx[(size_t)d * H + h]));
  L[i] = ex;
  atomicAdd(den + (size_t)d * H + h, ex);
}

__global__ __launch_bounds__(256) void k_invden(float* __restrict__ den) {
  int i = blockIdx.x * 256 + threadIdx.x;
  den[i] = 1.0f / den[i];
}

// ---------------- alpha-weighted aggregation (CSR, atomic-free) ----------------
template <int H, int F, bool SPLIT>
__global__ __launch_bounds__(256) void k_aggregate(
    const int* __restrict__ indptr, const int* __restrict__ ebyd,
    const int* __restrict__ ei, const float* __restrict__ L,
    const float* __restrict__ invden, const float* __restrict__ xl,
    const float* __restrict__ bias, float* __restrict__ out,
    bf16* __restrict__ outs) {
  constexpr int CPE = F / 256;
  const int n = blockIdx.x;
  const int tid = threadIdx.x;
  const int j0 = tid * CPE;
  const int h = j0 >> 8;
  const float invd = invden[(size_t)n * H + h];
  float acc[CPE] = {};
  const int p0 = indptr[n], p1 = indptr[n + 1];
  for (int p = p0; p < p1; ++p) {
    int e = ebyd[p];
    int s = (e < EE) ? ei[e] : (e - EE);
    float a = L[(size_t)p * H + h] * invd;
    const float* row = xl + (size_t)s * F + j0;
    #pragma unroll
    for (int q = 0; q < CPE; q += 4) {
      float4 v = *reinterpret_cast<const float4*>(row + q);
      acc[q + 0] = fmaf(a, v.x, acc[q + 0]);
      acc[q + 1] = fmaf(a, v.y, acc[q + 1]);
      acc[q + 2] = fmaf(a, v.z, acc[q + 2]);
      acc[q + 3] = fmaf(a, v.w, acc[q + 3]);
    }
  }
  #pragma unroll
  for (int q = 0; q < CPE; ++q) {
    float v = acc[q] + bias[j0 + q];
    if (SPLIT) {
      v = fmaxf(v, 0.0f);
      bf16 hi = (bf16)v;
      outs[(size_t)n * (2 * F) + j0 + q] = hi;
      outs[(size_t)n * (2 * F) + F + j0 + q] = (bf16)(v - (float)hi);
    } else {
      out[(size_t)n * F + j0 + q] = v;
    }
  }
}

// ---------------- pooling (batch sorted -> segmented mean) ----------------
__global__ __launch_bounds__(64) void k_gstart(const int* __restrict__ batch,
                                               int* __restrict__ gstart) {
  int g = threadIdx.x;
  int lo = 0, hi = NN;
  while (lo < hi) { int mid = (lo + hi) >> 1; if (batch[mid] < g) lo = mid + 1; else hi = mid; }
  gstart[g] = lo;
  if (g == 63) gstart[64] = NN;
}

__global__ __launch_bounds__(256) void k_pool2(const float* __restrict__ h2,
                                               const int* __restrict__ gstart,
                                               float* __restrict__ pooled) {
  int g = blockIdx.y;
  int j = blockIdx.x * 256 + threadIdx.x;
  int s = gstart[g], e2 = gstart[g + 1];
  float acc = 0.0f;
  for (int n = s; n < e2; ++n) acc += h2[(size_t)n * 1024 + j];
  pooled[(size_t)g * 1024 + j] = acc / fmaxf((float)(e2 - s), 1.0f);
}

__global__ __launch_bounds__(64) void k_head(const float* __restrict__ m2,
                                             const float* __restrict__ W3,
                                             const float* __restrict__ b3,
                                             float* __restrict__ out) {
  int g = threadIdx.x;
  float a = 0.0f;
  for (int k = 0; k < 256; ++k) a = fmaf(m2[(size_t)g * 256 + k], W3[k], a);
  a += b3[0];
  out[g] = 1.0f / (1.0f + expf(-a));
}

// ---------------- launch ----------------
extern "C" void kernel_launch(void* const* d_in, const int* in_sizes, int n_in,
                              void* d_out, int out_size, void* d_ws, size_t ws_size,
                              hipStream_t stream) {
  const float* x    = (const float*)d_in[0];
  const int*   ei   = (const int*)d_in[1];
  const float* ea   = (const float*)d_in[2];
  const int*   batch= (const int*)d_in[3];
  const float* Wl1  = (const float*)d_in[4];
  const float* bl1  = (const float*)d_in[5];
  const float* Wr1  = (const float*)d_in[6];
  const float* br1  = (const float*)d_in[7];
  const float* We1  = (const float*)d_in[8];
  const float* att1 = (const float*)d_in[9];
  const float* bias1= (const float*)d_in[10];
  const float* Wl2  = (const float*)d_in[11];
  const float* bl2  = (const float*)d_in[12];
  const float* Wr2  = (const float*)d_in[13];
  const float* br2  = (const float*)d_in[14];
  const float* We2  = (const float*)d_in[15];
  const float* att2 = (const float*)d_in[16];
  const float* bias2= (const float*)d_in[17];
  const float* W1   = (const float*)d_in[18];
  const float* b1   = (const float*)d_in[19];
  const float* W2   = (const float*)d_in[20];
  const float* b2   = (const float*)d_in[21];
  const float* W3   = (const float*)d_in[22];
  const float* b3   = (const float*)d_in[23];
  float* out = (float*)d_out;

  char* w = (char*)d_ws;
  size_t off = 0;
  auto take = [&](size_t b) { size_t r = off; off = (off + b + 255) & ~(size_t)255; return r; };

  size_t xl_off  = take((size_t)NN * 2048 * 4);   // layer1 xl; layer2 xl in [0,32MB), h2 in [32,64MB)
  size_t xr_off  = take((size_t)NN * 2048 * 4);
  size_t hs_off  = take((size_t)NN * 4096 * 2);   // split bf16 of relu(h1)
  size_t xs_off  = take((size_t)NN * 128 * 2);    // split bf16 of x
  size_t wl1s_off= take((size_t)2048 * 128 * 2);
  size_t wr1s_off= take((size_t)2048 * 128 * 2);
  size_t wl2s_off= take((size_t)1024 * 4096 * 2);
  size_t wr2s_off= take((size_t)1024 * 4096 * 2);
  size_t we1s_off= take((size_t)2048 * 64 * 2);
  size_t we2s_off= take((size_t)1024 * 64 * 2);
  size_t L_off   = take((size_t)ET * 8 * 4);
  size_t z1      = off;                           // ---- zero zone: cnt | den | max ----
  size_t cnt_off = take((size_t)NN * 4);
  size_t z2      = off;                           // ---- re-zeroed before layer 2 ----
  size_t den_off = take((size_t)NN * 8 * 4);
  size_t max_off = take((size_t)NN * 8 * 4);
  size_t z2e     = off;
  size_t ea_off  = take((size_t)NN * 32 * 4);
  size_t ip_off  = take((size_t)(NN + 1) * 4);
  size_t wp_off  = take((size_t)NN * 4);
  size_t eb_off  = take((size_t)ET * 4);
  size_t dp_off  = take((size_t)ET * 4);
  size_t gs_off  = take((size_t)65 * 4);
  size_t pool_off= take((size_t)GG * 1024 * 4);
  size_t m1_off  = take((size_t)GG * 512 * 4);
  size_t m2_off  = take((size_t)GG * 256 * 4);
  (void)ws_size; (void)n_in; (void)in_sizes; (void)out_size;

  float*    xlb   = (float*)(w + xl_off);
  float*    xrb   = (float*)(w + xr_off);
  float*    h2b   = (float*)(w + xl_off) + (size_t)NN * 1024;
  bf16*     hsb   = (bf16*)(w + hs_off);
  bf16*     xsb   = (bf16*)(w + xs_off);
  bf16*     wl1s  = (bf16*)(w + wl1s_off);
  bf16*     wr1s  = (bf16*)(w + wr1s_off);
  bf16*     wl2s  = (bf16*)(w + wl2s_off);
  bf16*     wr2s  = (bf16*)(w + wr2s_off);
  bf16*     we1s  = (bf16*)(w + we1s_off);
  bf16*     we2s  = (bf16*)(w + we2s_off);
  float*    Lb    = (float*)(w + L_off);
  int*      cntb  = (int*)(w + cnt_off);
  float*    denb  = (float*)(w + den_off);
  unsigned* maxb  = (unsigned*)(w + max_off);
  float*    eab   = (float*)(w + ea_off);
  int*      ipb   = (int*)(w + ip_off);
  int*      wpb   = (int*)(w + wp_off);
  int*      ebb   = (int*)(w + eb_off);
  int*      dpb   = (int*)(w + dp_off);
  int*      gsb   = (int*)(w + gs_off);
  float*    poolb = (float*)(w + pool_off);
  float*    m1b   = (float*)(w + m1_off);
  float*    m2b   = (float*)(w + m2_off);

  hipMemsetAsync(w + z1, 0, z2e - z1, stream);

  // CSR + self-loop edge attrs
  k_counts<<<ET / 256, 256, 0, stream>>>(ei, cntb);
  k_scan<<<1, 1024, 0, stream>>>(cntb, ipb, wpb);
  k_fill<<<ET / 256, 256, 0, stream>>>(ei, wpb, ebb, dpb);
  k_loopea<<<NN / 8, 256, 0, stream>>>(ipb, ebb, ea, eab);

  // split conversions
  k_split<<<(NN * 64 / 4 + 255) / 256, 256, 0, stream>>>(x, xsb, 64, NN * 64 / 4);
  k_split<<<(2048 * 64 / 4 + 255) / 256, 256, 0, stream>>>(Wl1, wl1s, 64, 2048 * 64 / 4);
  k_split<<<(2048 * 64 / 4 + 255) / 256, 256, 0, stream>>>(Wr1, wr1s, 64, 2048 * 64 / 4);
  k_split<<<(1024 * 2048 / 4 + 255) / 256, 256, 0, stream>>>(Wl2, wl2s, 2048, 1024 * 2048 / 4);
  k_split<<<(1024 * 2048 / 4 + 255) / 256, 256, 0, stream>>>(Wr2, wr2s, 2048, 1024 * 2048 / 4);
  k_split<<<(2048 * 32 / 4 + 255) / 256, 256, 0, stream>>>(We1, we1s, 32, 2048 * 32 / 4);
  k_split<<<(1024 * 32 / 4 + 255) / 256, 256, 0, stream>>>(We2, we2s, 32, 1024 * 32 / 4);

  // ---- layer 1 (H=8, F=2048): fused xl+xr GEMM, K'=3*64 ----
  gemm_dual<<<dim3(2 * 2048 / 128, NN / 128), 256, 0, stream>>>(
      xsb, wl1s, wr1s, bl1, br1, xlb, xrb, NN, 2048, 64);
  k_edge_logits_mfma<8, 2048><<<ET / 64, 256, 0, stream>>>(ebb, ei, ea, eab, xlb, xrb,
                                                           we1s, att1, Lb);
  k_segmax<8><<<ET * 8 / 256, 256, 0, stream>>>(Lb, dpb, maxb);
  k_exp_den<8><<<ET * 8 / 256, 256, 0, stream>>>(Lb, dpb, maxb, denb);
  k_invden<<<NN * 8 / 256, 256, 0, stream>>>(denb);
  k_aggregate<8, 2048, true><<<NN, 256, 0, stream>>>(ipb, ebb, ei, Lb, denb, xlb, bias1,
                                                     nullptr, hsb);

  // ---- layer 2 (H=4, F=1024): fused xl+xr GEMM, K'=3*2048 ----
  gemm_dual<<<dim3(2 * 1024 / 128, NN / 128), 256, 0, stream>>>(
      hsb, wl2s, wr2s, bl2, br2, xlb, xrb, NN, 1024, 2048);
  hipMemsetAsync(w + z2, 0, z2e - z2, stream);
  k_edge_logits_mfma<4, 1024><<<ET / 64, 256, 0, stream>>>(ebb, ei, ea, eab, xlb, xrb,
                                                           we2s, att2, Lb);
  k_segmax<4><<<ET * 4 / 256, 256, 0, stream>>>(Lb, dpb, maxb);
  k_exp_den<4><<<ET * 4 / 256, 256, 0, stream>>>(Lb, dpb, maxb, denb);
  k_invden<<<NN * 4 / 256, 256, 0, stream>>>(denb);
  k_aggregate<4, 1024, false><<<NN, 256, 0, stream>>>(ipb, ebb, ei, Lb, denb, xlb, bias2,
                                                      h2b, nullptr);

  // ---- pool + MLP ----
  k_gstart<<<1, 64, 0, stream>>>(batch, gsb);
  k_pool2<<<dim3(4, GG), 256, 0, stream>>>(h2b, gsb, poolb);
  gemm_nt<<<dim3(512 / 64, 1), 256, 0, stream>>>(poolb, W1, b1, m1b, GG, 512, 1024, 1);
  gemm_nt<<<dim3(256 / 64, 1), 256, 0, stream>>>(m1b, W2, b2, m2b, GG, 256, 512, 1);
  k_head<<<1, 64, 0, stream>>>(m2b, W3, b3, out);
}

// Round 11
// 941.141 us; speedup vs baseline: 2.1498x; 1.0559x over previous
//
#include <hip/hip_runtime.h>
#include <math.h>

// ---------------- problem constants ----------------
constexpr int NN = 8192;          // nodes
constexpr int EE = 65536;         // original edges
constexpr int ET = EE + NN;       // edges incl self loops = 73728
constexpr int GG = 64;            // graphs
constexpr float SLOPE = 0.2f;

using bf16 = __bf16;
using bf16x8 = __bf16 __attribute__((ext_vector_type(8)));
using bf16x4 = __bf16 __attribute__((ext_vector_type(4)));
using f32x4v = float __attribute__((ext_vector_type(4)));

// ---------------- helpers ----------------
__device__ __forceinline__ unsigned enc_f(float f) {
  unsigned u = __float_as_uint(f);
  return (u & 0x80000000u) ? ~u : (u | 0x80000000u);
}
__device__ __forceinline__ float dec_f(unsigned e) {
  return (e & 0x80000000u) ? __uint_as_float(e & 0x7FFFFFFFu) : __uint_as_float(~e);
}

// async global->LDS, 16B per lane. LDS dest must be WAVE-UNIFORM base (+lane*16 by HW).
__device__ __forceinline__ void gl2lds16(const void* g, void* l) {
  __builtin_amdgcn_global_load_lds(
      (const __attribute__((address_space(1))) void*)g,
      (__attribute__((address_space(3))) void*)l, 16, 0, 0);
}

// ---------------- CSR build (edges sorted by dst) ----------------
__global__ __launch_bounds__(256) void k_counts(const int* __restrict__ ei,
                                                int* __restrict__ cnt) {
  int e = blockIdx.x * 256 + threadIdx.x;        // ET
  int d = (e < EE) ? ei[EE + e] : (e - EE);
  atomicAdd(cnt + d, 1);
}

__global__ __launch_bounds__(1024) void k_scan(const int* __restrict__ cnt,
                                               int* __restrict__ indptr,
                                               int* __restrict__ wpos) {
  __shared__ int sums[1024];
  int t = threadIdx.x;
  int local[8];
  int s = 0;
  #pragma unroll
  for (int i = 0; i < 8; ++i) { local[i] = s; s += cnt[t * 8 + i]; }
  sums[t] = s;
  __syncthreads();
  for (int off = 1; off < 1024; off <<= 1) {
    int v = (t >= off) ? sums[t - off] : 0;
    __syncthreads();
    sums[t] += v;
    __syncthreads();
  }
  int base = (t == 0) ? 0 : sums[t - 1];
  #pragma unroll
  for (int i = 0; i < 8; ++i) {
    int v = base + local[i];
    indptr[t * 8 + i] = v;
    wpos[t * 8 + i] = v;
  }
  if (t == 1023) indptr[NN] = sums[1023];
}

__global__ __launch_bounds__(256) void k_fill(const int* __restrict__ ei,
                                              int* __restrict__ wpos,
                                              int* __restrict__ ebyd,
                                              int* __restrict__ dstp) {
  int e = blockIdx.x * 256 + threadIdx.x;        // ET
  int d = (e < EE) ? ei[EE + e] : (e - EE);
  int idx = atomicAdd(wpos + d, 1);
  ebyd[idx] = e;
  dstp[idx] = d;
}

// self-loop edge attr = mean of incoming original edge attrs (atomic-free, via CSR)
__global__ __launch_bounds__(256) void k_loopea(const int* __restrict__ ip,
                                                const int* __restrict__ ebyd,
                                                const float* __restrict__ ea,
                                                float* __restrict__ easum) {
  int node = blockIdx.x * 8 + (threadIdx.x >> 5);
  int k = threadIdx.x & 31;
  float acc = 0.0f, deg = 0.0f;
  int p0 = ip[node], p1 = ip[node + 1];
  for (int p = p0; p < p1; ++p) {
    int e = ebyd[p];
    if (e < EE) { acc += ea[(size_t)e * 32 + k]; deg += 1.0f; }
  }
  easum[(size_t)node * 32 + k] = acc / fmaxf(deg, 1.0f);
}

// ---------------- fp32 -> split bf16 [hi | lo], row-major [M][2K] ----------------
__global__ __launch_bounds__(256) void k_split(const float* __restrict__ in,
                                               bf16* __restrict__ out,
                                               int K, int total4) {
  int i = blockIdx.x * 256 + threadIdx.x;
  if (i >= total4) return;
  int K4 = K >> 2;
  int m = i / K4, k4 = (i - m * K4) << 2;
  float4 v = *reinterpret_cast<const float4*>(in + (size_t)m * K + k4);
  float vv[4] = {v.x, v.y, v.z, v.w};
  bf16x4 hi, lo;
  #pragma unroll
  for (int u = 0; u < 4; ++u) {
    bf16 h = (bf16)vv[u];
    hi[u] = h;
    lo[u] = (bf16)(vv[u] - (float)h);
  }
  *reinterpret_cast<bf16x4*>(out + (size_t)m * 2 * K + k4) = hi;
  *reinterpret_cast<bf16x4*>(out + (size_t)m * 2 * K + K + k4) = lo;
}

// ---------------- fused dual-B split-bf16 MFMA GEMM (compile-time K) ----------------
// C1 = A@B1^T + bias1 AND C2 = A@B2^T + bias2 in one dispatch (A fetched once).
// T1 XCD swizzle; n-fastest decomposition. Ko is a template parameter so the
// 3-term split walk is three affine loops with compile-time trip counts
// (removes runtime ka/kb selects + runtime ld -> compiler strength-reduces and
// pipelines; same MFMA order as the validated kernel -> bit-exact).
template <int Ko>
__global__ __launch_bounds__(256) void gemm_dual(
    const bf16* __restrict__ A, const bf16* __restrict__ B1,
    const bf16* __restrict__ B2, const float* __restrict__ bias1,
    const float* __restrict__ bias2, float* __restrict__ C1,
    float* __restrict__ C2, int M, int Nc) {
  __shared__ __attribute__((aligned(16))) bf16 As[128][32];
  __shared__ __attribute__((aligned(16))) bf16 Bs[128][32];
  const int tid = threadIdx.x;
  const int wave = tid >> 6, lane = tid & 63;
  const int wr = wave >> 1, wc = wave & 1;
  const int l16 = lane & 15, lk = lane >> 4;

  // ---- swizzled block -> (m-tile, n-tile, which-B) ----
  const int nwg = gridDim.x * gridDim.y;
  const int bid = blockIdx.y * gridDim.x + blockIdx.x;
  const int cpx = nwg >> 3;                    // blocks per XCD (nwg % 8 == 0)
  const int swz = (bid & 7) * cpx + (bid >> 3);
  const int tn2 = swz % gridDim.x;             // n-fastest within XCD band
  const int tm  = swz / gridDim.x;
  const int ntn = gridDim.x >> 1;              // n-tiles per B matrix
  const bool second = tn2 >= ntn;
  const int m0 = tm * 128;
  const int n0 = (second ? tn2 - ntn : tn2) * 128;
  const bf16* B = second ? B2 : B1;
  const float* bias = second ? bias2 : bias1;
  float* C = second ? C2 : C1;

  constexpr int ld = 2 * Ko;
  const int r0 = tid >> 2, c8 = (tid & 3) * 8;

  f32x4v acc[4][4] = {};
  const bf16* Abase = A + (size_t)m0 * ld;
  const bf16* Bbase = B + (size_t)n0 * ld;

  auto kstep = [&](int ka, int kb) {
    #pragma unroll
    for (int i = 0; i < 2; ++i) {
      int row = i * 64 + r0;
      bf16* abase = &As[0][0] + ((size_t)(i * 256 + wave * 64)) * 8;
      bf16* bbase = &Bs[0][0] + ((size_t)(i * 256 + wave * 64)) * 8;
      gl2lds16(Abase + (size_t)row * ld + ka + c8, abase);
      gl2lds16(Bbase + (size_t)row * ld + kb + c8, bbase);
    }
    __syncthreads();
    bf16x8 af[4], bfr[4];
    #pragma unroll
    for (int mi = 0; mi < 4; ++mi)
      af[mi] = *reinterpret_cast<const bf16x8*>(&As[wr * 64 + mi * 16 + l16][lk * 8]);
    #pragma unroll
    for (int ni = 0; ni < 4; ++ni)
      bfr[ni] = *reinterpret_cast<const bf16x8*>(&Bs[wc * 64 + ni * 16 + l16][lk * 8]);
    #pragma unroll
    for (int mi = 0; mi < 4; ++mi)
      #pragma unroll
      for (int ni = 0; ni < 4; ++ni)
        acc[mi][ni] = __builtin_amdgcn_mfma_f32_16x16x32_bf16(af[mi], bfr[ni],
                                                              acc[mi][ni], 0, 0, 0);
    __syncthreads();
  };

  for (int k = 0; k < Ko; k += 32) kstep(k, k);            // A_hi · B_hi
  for (int k = 0; k < Ko; k += 32) kstep(k, Ko + k);       // A_hi · B_lo
  for (int k = 0; k < Ko; k += 32) kstep(Ko + k, k);       // A_lo · B_hi

  // C/D layout (m89-verified): col = lane&15, row = (lane>>4)*4 + reg
  #pragma unroll
  for (int mi = 0; mi < 4; ++mi) {
    #pragma unroll
    for (int ni = 0; ni < 4; ++ni) {
      int col = n0 + wc * 64 + ni * 16 + l16;
      float bv = bias ? bias[col] : 0.0f;
      #pragma unroll
      for (int j = 0; j < 4; ++j) {
        int row = m0 + wr * 64 + mi * 16 + lk * 4 + j;
        C[(size_t)row * Nc + col] = acc[mi][ni][j] + bv;
      }
    }
  }
}

// ---------------- fp32 GEMM (tiny MLP head only) ----------------
__global__ __launch_bounds__(256) void gemm_nt(
    const float* __restrict__ A, const float* __restrict__ Bm,
    const float* __restrict__ bias, float* __restrict__ Cm,
    int M, int Nc, int K, int act) {
  __shared__ float As[16][68];
  __shared__ float Bs[16][68];
  const int tid = threadIdx.x;
  const int tx = tid & 15, ty = tid >> 4;
  const int m0 = blockIdx.y * 64, n0 = blockIdx.x * 64;
  float acc[4][4] = {};
  for (int k0 = 0; k0 < K; k0 += 16) {
    int r = tid >> 2;
    int c4 = (tid & 3) * 4;
    float4 va = *reinterpret_cast<const float4*>(A + (size_t)(m0 + r) * K + k0 + c4);
    float4 vb = *reinterpret_cast<const float4*>(Bm + (size_t)(n0 + r) * K + k0 + c4);
    As[c4 + 0][r] = va.x; As[c4 + 1][r] = va.y; As[c4 + 2][r] = va.z; As[c4 + 3][r] = va.w;
    Bs[c4 + 0][r] = vb.x; Bs[c4 + 1][r] = vb.y; Bs[c4 + 2][r] = vb.z; Bs[c4 + 3][r] = vb.w;
    __syncthreads();
    #pragma unroll
    for (int k = 0; k < 16; ++k) {
      float a[4], b[4];
      #pragma unroll
      for (int i = 0; i < 4; ++i) a[i] = As[k][ty * 4 + i];
      #pragma unroll
      for (int j = 0; j < 4; ++j) b[j] = Bs[k][tx * 4 + j];
      #pragma unroll
      for (int i = 0; i < 4; ++i)
        #pragma unroll
        for (int j = 0; j < 4; ++j) acc[i][j] = fmaf(a[i], b[j], acc[i][j]);
    }
    __syncthreads();
  }
  #pragma unroll
  for (int i = 0; i < 4; ++i) {
    int m = m0 + ty * 4 + i;
    #pragma unroll
    for (int j = 0; j < 4; ++j) {
      int n = n0 + tx * 4 + j;
      float v = acc[i][j] + (bias ? bias[n] : 0.0f);
      if (act == 1) v = fmaxf(v, 0.0f);
      Cm[(size_t)m * Nc + n] = v;
    }
  }
}

// ---------------- per-edge logit pass, MFMA ee ----------------
// Block: 64 edges (dst-sorted), 4 waves x 16 edges. Per 64-chan chunk:
// ee tile via 3-term split-bf16 mfma_16x16x32 (ea[hi|lo] x We[hi|lo]),
// then epilogue on C-layout: chan = lane&15 (coalesced), edge = (lane>>4)*4+j.
template <int H, int F>
__global__ __launch_bounds__(256) void k_edge_logits_mfma(
    const int* __restrict__ ebyd, const int* __restrict__ ei,
    const float* __restrict__ edge_attr, const float* __restrict__ loop_ea,
    const float* __restrict__ xl, const float* __restrict__ xr,
    const bf16* __restrict__ Wes,   // [F][64] split hi|lo
    const float* __restrict__ att,  // [F]
    float* __restrict__ L) {
  __shared__ __attribute__((aligned(16))) bf16 ea_s[64][72];  // 144B row: 16B-aligned, 2-way bank alias (free)
  __shared__ __attribute__((aligned(16))) bf16 we_s[64][72];
  __shared__ int ss[64], dd[64];
  const int tid = threadIdx.x;
  const int wave = tid >> 6, lane = tid & 63;
  const int l16 = lane & 15, lk = lane >> 4;
  const int pbase = blockIdx.x * 64;

  if (tid < 64) {
    int e = ebyd[pbase + tid];
    int s, d;
    if (e < EE) { s = ei[e]; d = ei[EE + e]; }
    else { s = d = e - EE; }
    ss[tid] = s; dd[tid] = d;
  }
  {
    int edge = tid >> 2, a0 = (tid & 3) * 8;
    int e = ebyd[pbase + edge];
    const float* srcp = (e < EE) ? (edge_attr + (size_t)e * 32 + a0)
                                 : (loop_ea + (size_t)(e - EE) * 32 + a0);
    float4 v0 = *reinterpret_cast<const float4*>(srcp);
    float4 v1 = *reinterpret_cast<const float4*>(srcp + 4);
    float vv[8] = {v0.x, v0.y, v0.z, v0.w, v1.x, v1.y, v1.z, v1.w};
    bf16x8 hi, lo;
    #pragma unroll
    for (int u = 0; u < 8; ++u) {
      bf16 h = (bf16)vv[u];
      hi[u] = h; lo[u] = (bf16)(vv[u] - (float)h);
    }
    *reinterpret_cast<bf16x8*>(&ea_s[edge][a0]) = hi;
    *reinterpret_cast<bf16x8*>(&ea_s[edge][32 + a0]) = lo;
  }
  __syncthreads();

  // hoist A-frags (constant across chunks) + per-lane row pointers
  bf16x8 af_hi = *reinterpret_cast<const bf16x8*>(&ea_s[wave * 16 + l16][lk * 8]);
  bf16x8 af_lo = *reinterpret_cast<const bf16x8*>(&ea_s[wave * 16 + l16][32 + lk * 8]);
  const float* xlp[4];
  const float* xrp[4];
  #pragma unroll
  for (int j = 0; j < 4; ++j) {
    int es = wave * 16 + lk * 4 + j;
    xlp[j] = xl + (size_t)ss[es] * F;
    xrp[j] = xr + (size_t)dd[es] * F;
  }

  float lg[4] = {};
  for (int jc = 0; jc < F; jc += 64) {
    __syncthreads();               // protect we_s from previous chunk's reads
    {
      int row = tid >> 2, c0 = (tid & 3) * 16;
      const bf16* gp = Wes + (size_t)(jc + row) * 64 + c0;
      bf16x8 w0 = *reinterpret_cast<const bf16x8*>(gp);
      bf16x8 w1 = *reinterpret_cast<const bf16x8*>(gp + 8);
      *reinterpret_cast<bf16x8*>(&we_s[row][c0]) = w0;
      *reinterpret_cast<bf16x8*>(&we_s[row][c0 + 8]) = w1;
    }
    __syncthreads();
    #pragma unroll
    for (int ni = 0; ni < 4; ++ni) {
      bf16x8 bh = *reinterpret_cast<const bf16x8*>(&we_s[ni * 16 + l16][lk * 8]);
      bf16x8 bl = *reinterpret_cast<const bf16x8*>(&we_s[ni * 16 + l16][32 + lk * 8]);
      f32x4v acc = {};
      acc = __builtin_amdgcn_mfma_f32_16x16x32_bf16(af_hi, bh, acc, 0, 0, 0);
      acc = __builtin_amdgcn_mfma_f32_16x16x32_bf16(af_lo, bh, acc, 0, 0, 0);
      acc = __builtin_amdgcn_mfma_f32_16x16x32_bf16(af_hi, bl, acc, 0, 0, 0);
      int chan = jc + ni * 16 + l16;
      float av = att[chan];
      #pragma unroll
      for (int j = 0; j < 4; ++j) {
        float m = xlp[j][chan] + xrp[j][chan] + acc[j];
        m = (m > 0.0f) ? m : (SLOPE * m);
        lg[j] = fmaf(m, av, lg[j]);
      }
    }
    if ((jc & 255) == 192) {       // finished a 256-chan head
      int h = jc >> 8;
      #pragma unroll
      for (int j = 0; j < 4; ++j) {
        float r = lg[j];
        r += __shfl_xor(r, 1);
        r += __shfl_xor(r, 2);
        r += __shfl_xor(r, 4);
        r += __shfl_xor(r, 8);
        if (l16 == 0) L[(size_t)(pbase + wave * 16 + lk * 4 + j) * H + h] = r;
        lg[j] = 0.0f;
      }
    }
  }
}

// ---------------- segment softmax ----------------
template <int H>
__global__ __launch_bounds__(256) void k_segmax(const float* __restrict__ L,
                                                const int* __restrict__ dstp,
                                                unsigned* __restrict__ mx) {
  int i = blockIdx.x * 256 + threadIdx.x;
  int p = i / H, h = i - p * H;
  atomicMax(mx + (size_t)dstp[p] * H + h, enc_f(L[i]));
}

template <int H>
__global__ __launch_bounds__(256) void k_exp_den(float* __restrict__ L,
                                                 const int* __restrict__ dstp,
                                                 const unsigned* __restrict__ mx,
                                                 float* __restrict__ den) {
  int i = blockIdx.x * 256 + threadIdx.x;
  int p = i / H, h = i - p * H;
  int d = dstp[p];
  float ex = expf(L[i] - dec_f(mx[(size_t)d * H + h]));
  L[i] = ex;
  atomicAdd(den + (size_t)d * H + h, ex);
}

__global__ __launch_bounds__(256) void k_invden(float* __restrict__ den) {
  int i = blockIdx.x * 256 + threadIdx.x;
  den[i] = 1.0f / den[i];
}

// ---------------- alpha-weighted aggregation (CSR, atomic-free) ----------------
template <int H, int F, bool SPLIT>
__global__ __launch_bounds__(256) void k_aggregate(
    const int* __restrict__ indptr, const int* __restrict__ ebyd,
    const int* __restrict__ ei, const float* __restrict__ L,
    const float* __restrict__ invden, const float* __restrict__ xl,
    const float* __restrict__ bias, float* __restrict__ out,
    bf16* __restrict__ outs) {
  constexpr int CPE = F / 256;
  const int n = blockIdx.x;
  const int tid = threadIdx.x;
  const int j0 = tid * CPE;
  const int h = j0 >> 8;
  const float invd = invden[(size_t)n * H + h];
  float acc[CPE] = {};
  const int p0 = indptr[n], p1 = indptr[n + 1];
  for (int p = p0; p < p1; ++p) {
    int e = ebyd[p];
    int s = (e < EE) ? ei[e] : (e - EE);
    float a = L[(size_t)p * H + h] * invd;
    const float* row = xl + (size_t)s * F + j0;
    #pragma unroll
    for (int q = 0; q < CPE; q += 4) {
      float4 v = *reinterpret_cast<const float4*>(row + q);
      acc[q + 0] = fmaf(a, v.x, acc[q + 0]);
      acc[q + 1] = fmaf(a, v.y, acc[q + 1]);
      acc[q + 2] = fmaf(a, v.z, acc[q + 2]);
      acc[q + 3] = fmaf(a, v.w, acc[q + 3]);
    }
  }
  #pragma unroll
  for (int q = 0; q < CPE; ++q) {
    float v = acc[q] + bias[j0 + q];
    if (SPLIT) {
      v = fmaxf(v, 0.0f);
      bf16 hi = (bf16)v;
      outs[(size_t)n * (2 * F) + j0 + q] = hi;
      outs[(size_t)n * (2 * F) + F + j0 + q] = (bf16)(v - (float)hi);
    } else {
      out[(size_t)n * F + j0 + q] = v;
    }
  }
}

// ---------------- pooling (batch sorted -> segmented mean) ----------------
__global__ __launch_bounds__(64) void k_gstart(const int* __restrict__ batch,
                                               int* __restrict__ gstart) {
  int g = threadIdx.x;
  int lo = 0, hi = NN;
  while (lo < hi) { int mid = (lo + hi) >> 1; if (batch[mid] < g) lo = mid + 1; else hi = mid; }
  gstart[g] = lo;
  if (g == 63) gstart[64] = NN;
}

__global__ __launch_bounds__(256) void k_pool2(const float* __restrict__ h2,
                                               const int* __restrict__ gstart,
                                               float* __restrict__ pooled) {
  int g = blockIdx.y;
  int j = blockIdx.x * 256 + threadIdx.x;
  int s = gstart[g], e2 = gstart[g + 1];
  float acc = 0.0f;
  for (int n = s; n < e2; ++n) acc += h2[(size_t)n * 1024 + j];
  pooled[(size_t)g * 1024 + j] = acc / fmaxf((float)(e2 - s), 1.0f);
}

__global__ __launch_bounds__(64) void k_head(const float* __restrict__ m2,
                                             const float* __restrict__ W3,
                                             const float* __restrict__ b3,
                                             float* __restrict__ out) {
  int g = threadIdx.x;
  float a = 0.0f;
  for (int k = 0; k < 256; ++k) a = fmaf(m2[(size_t)g * 256 + k], W3[k], a);
  a += b3[0];
  out[g] = 1.0f / (1.0f + expf(-a));
}

// ---------------- launch ----------------
extern "C" void kernel_launch(void* const* d_in, const int* in_sizes, int n_in,
                              void* d_out, int out_size, void* d_ws, size_t ws_size,
                              hipStream_t stream) {
  const float* x    = (const float*)d_in[0];
  const int*   ei   = (const int*)d_in[1];
  const float* ea   = (const float*)d_in[2];
  const int*   batch= (const int*)d_in[3];
  const float* Wl1  = (const float*)d_in[4];
  const float* bl1  = (const float*)d_in[5];
  const float* Wr1  = (const float*)d_in[6];
  const float* br1  = (const float*)d_in[7];
  const float* We1  = (const float*)d_in[8];
  const float* att1 = (const float*)d_in[9];
  const float* bias1= (const float*)d_in[10];
  const float* Wl2  = (const float*)d_in[11];
  const float* bl2  = (const float*)d_in[12];
  const float* Wr2  = (const float*)d_in[13];
  const float* br2  = (const float*)d_in[14];
  const float* We2  = (const float*)d_in[15];
  const float* att2 = (const float*)d_in[16];
  const float* bias2= (const float*)d_in[17];
  const float* W1   = (const float*)d_in[18];
  const float* b1   = (const float*)d_in[19];
  const float* W2   = (const float*)d_in[20];
  const float* b2   = (const float*)d_in[21];
  const float* W3   = (const float*)d_in[22];
  const float* b3   = (const float*)d_in[23];
  float* out = (float*)d_out;

  char* w = (char*)d_ws;
  size_t off = 0;
  auto take = [&](size_t b) { size_t r = off; off = (off + b + 255) & ~(size_t)255; return r; };

  size_t xl_off  = take((size_t)NN * 2048 * 4);   // layer1 xl; layer2 xl in [0,32MB), h2 in [32,64MB)
  size_t xr_off  = take((size_t)NN * 2048 * 4);
  size_t hs_off  = take((size_t)NN * 4096 * 2);   // split bf16 of relu(h1)
  size_t xs_off  = take((size_t)NN * 128 * 2);    // split bf16 of x
  size_t wl1s_off= take((size_t)2048 * 128 * 2);
  size_t wr1s_off= take((size_t)2048 * 128 * 2);
  size_t wl2s_off= take((size_t)1024 * 4096 * 2);
  size_t wr2s_off= take((size_t)1024 * 4096 * 2);
  size_t we1s_off= take((size_t)2048 * 64 * 2);
  size_t we2s_off= take((size_t)1024 * 64 * 2);
  size_t L_off   = take((size_t)ET * 8 * 4);
  size_t z1      = off;                           // ---- zero zone: cnt | den | max ----
  size_t cnt_off = take((size_t)NN * 4);
  size_t z2      = off;                           // ---- re-zeroed before layer 2 ----
  size_t den_off = take((size_t)NN * 8 * 4);
  size_t max_off = take((size_t)NN * 8 * 4);
  size_t z2e     = off;
  size_t ea_off  = take((size_t)NN * 32 * 4);
  size_t ip_off  = take((size_t)(NN + 1) * 4);
  size_t wp_off  = take((size_t)NN * 4);
  size_t eb_off  = take((size_t)ET * 4);
  size_t dp_off  = take((size_t)ET * 4);
  size_t gs_off  = take((size_t)65 * 4);
  size_t pool_off= take((size_t)GG * 1024 * 4);
  size_t m1_off  = take((size_t)GG * 512 * 4);
  size_t m2_off  = take((size_t)GG * 256 * 4);
  (void)ws_size; (void)n_in; (void)in_sizes; (void)out_size;

  float*    xlb   = (float*)(w + xl_off);
  float*    xrb   = (float*)(w + xr_off);
  float*    h2b   = (float*)(w + xl_off) + (size_t)NN * 1024;
  bf16*     hsb   = (bf16*)(w + hs_off);
  bf16*     xsb   = (bf16*)(w + xs_off);
  bf16*     wl1s  = (bf16*)(w + wl1s_off);
  bf16*     wr1s  = (bf16*)(w + wr1s_off);
  bf16*     wl2s  = (bf16*)(w + wl2s_off);
  bf16*     wr2s  = (bf16*)(w + wr2s_off);
  bf16*     we1s  = (bf16*)(w + we1s_off);
  bf16*     we2s  = (bf16*)(w + we2s_off);
  float*    Lb    = (float*)(w + L_off);
  int*      cntb  = (int*)(w + cnt_off);
  float*    denb  = (float*)(w + den_off);
  unsigned* maxb  = (unsigned*)(w + max_off);
  float*    eab   = (float*)(w + ea_off);
  int*      ipb   = (int*)(w + ip_off);
  int*      wpb   = (int*)(w + wp_off);
  int*      ebb   = (int*)(w + eb_off);
  int*      dpb   = (int*)(w + dp_off);
  int*      gsb   = (int*)(w + gs_off);
  float*    poolb = (float*)(w + pool_off);
  float*    m1b   = (float*)(w + m1_off);
  float*    m2b   = (float*)(w + m2_off);

  hipMemsetAsync(w + z1, 0, z2e - z1, stream);

  // CSR + self-loop edge attrs
  k_counts<<<ET / 256, 256, 0, stream>>>(ei, cntb);
  k_scan<<<1, 1024, 0, stream>>>(cntb, ipb, wpb);
  k_fill<<<ET / 256, 256, 0, stream>>>(ei, wpb, ebb, dpb);
  k_loopea<<<NN / 8, 256, 0, stream>>>(ipb, ebb, ea, eab);

  // split conversions
  k_split<<<(NN * 64 / 4 + 255) / 256, 256, 0, stream>>>(x, xsb, 64, NN * 64 / 4);
  k_split<<<(2048 * 64 / 4 + 255) / 256, 256, 0, stream>>>(Wl1, wl1s, 64, 2048 * 64 / 4);
  k_split<<<(2048 * 64 / 4 + 255) / 256, 256, 0, stream>>>(Wr1, wr1s, 64, 2048 * 64 / 4);
  k_split<<<(1024 * 2048 / 4 + 255) / 256, 256, 0, stream>>>(Wl2, wl2s, 2048, 1024 * 2048 / 4);
  k_split<<<(1024 * 2048 / 4 + 255) / 256, 256, 0, stream>>>(Wr2, wr2s, 2048, 1024 * 2048 / 4);
  k_split<<<(2048 * 32 / 4 + 255) / 256, 256, 0, stream>>>(We1, we1s, 32, 2048 * 32 / 4);
  k_split<<<(1024 * 32 / 4 + 255) / 256, 256, 0, stream>>>(We2, we2s, 32, 1024 * 32 / 4);

  // ---- layer 1 (H=8, F=2048): fused xl+xr GEMM, K'=3*64 ----
  gemm_dual<64><<<dim3(2 * 2048 / 128, NN / 128), 256, 0, stream>>>(
      xsb, wl1s, wr1s, bl1, br1, xlb, xrb, NN, 2048);
  k_edge_logits_mfma<8, 2048><<<ET / 64, 256, 0, stream>>>(ebb, ei, ea, eab, xlb, xrb,
                                                           we1s, att1, Lb);
  k_segmax<8><<<ET * 8 / 256, 256, 0, stream>>>(Lb, dpb, maxb);
  k_exp_den<8><<<ET * 8 / 256, 256, 0, stream>>>(Lb, dpb, maxb, denb);
  k_invden<<<NN * 8 / 256, 256, 0, stream>>>(denb);
  k_aggregate<8, 2048, true><<<NN, 256, 0, stream>>>(ipb, ebb, ei, Lb, denb, xlb, bias1,
                                                     nullptr, hsb);

  // ---- layer 2 (H=4, F=1024): fused xl+xr GEMM, K'=3*2048 ----
  gemm_dual<2048><<<dim3(2 * 1024 / 128, NN / 128), 256, 0, stream>>>(
      hsb, wl2s, wr2s, bl2, br2, xlb, xrb, NN, 1024);
  hipMemsetAsync(w + z2, 0, z2e - z2, stream);
  k_edge_logits_mfma<4, 1024><<<ET / 64, 256, 0, stream>>>(ebb, ei, ea, eab, xlb, xrb,
                                                           we2s, att2, Lb);
  k_segmax<4><<<ET * 4 / 256, 256, 0, stream>>>(Lb, dpb, maxb);
  k_exp_den<4><<<ET * 4 / 256, 256, 0, stream>>>(Lb, dpb, maxb, denb);
  k_invden<<<NN * 4 / 256, 256, 0, stream>>>(denb);
  k_aggregate<4, 1024, false><<<NN, 256, 0, stream>>>(ipb, ebb, ei, Lb, denb, xlb, bias2,
                                                      h2b, nullptr);

  // ---- pool + MLP ----
  k_gstart<<<1, 64, 0, stream>>>(batch, gsb);
  k_pool2<<<dim3(4, GG), 256, 0, stream>>>(h2b, gsb, poolb);
  gemm_nt<<<dim3(512 / 64, 1), 256, 0, stream>>>(poolb, W1, b1, m1b, GG, 512, 1024, 1);
  gemm_nt<<<dim3(256 / 64, 1), 256, 0, stream>>>(m1b, W2, b2, m2b, GG, 256, 512, 1);
  k_head<<<1, 64, 0, stream>>>(m2b, W3, b3, out);
}